// Round 10
// baseline (1192.814 us; speedup 1.0000x reference)
//
#include <hip/hip_runtime.h>
#include <math.h>

#define T_ 256
#define B_ 32
#define E_ 256
#define HD_ 256
#define NG_ 1024
#define K_ 12
#define START_ 10
#define STOP_ 11
#define NEG_ -10000.0f
#define MAGICU 0x40000000u   // 2.0f — |h|<1 so h can never be this bit pattern

typedef float f4_t __attribute__((ext_vector_type(4)));

__device__ __forceinline__ float sigf(float x) { return 1.0f / (1.0f + expf(-x)); }

// ---------- fused prep: hex sentinel fill + Whh^T + token gather + gcnt/fcnt zero ----------
__global__ void prep(const int* __restrict__ sent, const int* __restrict__ lens,
                     int* __restrict__ tokA, const float* __restrict__ Wf,
                     const float* __restrict__ Wb, float* __restrict__ WT,
                     float* __restrict__ hex, int* __restrict__ gcnt) {
    const int b = blockIdx.x, tid = threadIdx.x;
    if (b < 4096) {
        // hex sentinel fill: 4096 blocks x 256 thr x 16 B = 16 MB
        float4 m = make_float4(2.0f, 2.0f, 2.0f, 2.0f);
        ((float4*)hex)[b * 256 + tid] = m;
        if (b == 0 && tid < 136) gcnt[tid] = 0;   // 128 gcnt + 8 fcnt in d_out preds region
    } else if (b < 4608) {
        // Whh^T into [dir][k][u*4+gate] (unit-major gate packing)
        int b2 = b - 4096;
        int dir = b2 >> 8, k = b2 & 255, u = tid;
        const float* W = dir ? Wb : Wf;
        float4 v;
        v.x = W[(0 * HD_ + u) * HD_ + k];   // i
        v.y = W[(1 * HD_ + u) * HD_ + k];   // f
        v.z = W[(2 * HD_ + u) * HD_ + k];   // g
        v.w = W[(3 * HD_ + u) * HD_ + k];   // o
        ((float4*)(WT + ((size_t)dir * 256 + k) * NG_))[u] = v;
    } else {
        // token gather (bwd dir reversed within each sequence length)
        int e = (b - 4608) * 256 + tid;      // 0..16383 = [dir][t*32+b]
        int dir = e >> 13, m = e & 8191, t = m >> 5, bb = m & 31;
        int len = lens[bb];
        int tt = dir ? (t < len ? len - 1 - t : t) : t;
        tokA[e] = sent[bb * T_ + tt];
    }
}

// ---------- mega-kernel, 4 roles by blockIdx (r8 protocol; r9's sc0sc1-poll
// experiment reverted — polls use the proven __hip_atomic agent path):
//   [0,64)      v11 lstm recurrence (proven exchange, gcnt-gated G prefetch)
//   [64,1088)   in_gemm producers: sc0 sc1 write-through G stores + vmcnt(0)
//               drain + barrier + atomicAdd release (r6-proven)
//   [1088,1344) feat blocks: r8 polls; now publish feats with the SAME producer
//               discipline (sc0 sc1 stores + vmcnt + barrier + release fcnt add)
//   1344        viterbi: per-32t-chunk fcnt gate (tid0 RELAXED poll + sleep +
//               bail), coop-load feats chunk into LDS, identical DP + backtrace.
// All spins carry bail counters -> no hang possible.
__global__ __launch_bounds__(512, 1) void mega(
    const float* __restrict__ emb, const int* __restrict__ tokA,
    const float* __restrict__ Wih_f, const float* __restrict__ Wih_b,
    const float* __restrict__ bih_f, const float* __restrict__ bhh_f,
    const float* __restrict__ bih_b, const float* __restrict__ bhh_b,
    const float* __restrict__ WhhT, float* __restrict__ G,
    const float* __restrict__ h0, const float* __restrict__ c0,
    const int* __restrict__ lens, float* __restrict__ hex,
    int* __restrict__ gcnt, const float* __restrict__ Wout,
    const float* __restrict__ bout, float* __restrict__ feats,
    const float* __restrict__ trans, float* __restrict__ out) {
    __shared__ float smem[24832];                // 99328 B, carved per role
    const int tid = threadIdx.x;

    if (blockIdx.x == 1344) {
        // ================= viterbi role =================
        unsigned char* bp = (unsigned char*)smem;     // [256][32][6] nibble bps, 48 KB
        float* fv = smem + 12288;                     // [2][32][16]
        float* tl = smem + 13312;                     // [12][16]
        int* best_last = (int*)(smem + 13504);        // [32]
        float* fbuf = smem + 13536;                   // [16][32][13] chunk feats
        int* fcnt = gcnt + 128;
        const int b = tid >> 4, lane = tid & 15;
        if (tid < K_ * K_) tl[(tid / 12) * 16 + (tid % 12)] = trans[tid];
        if (lane < K_) fv[b * 16 + lane] = (lane == START_) ? 0.f : NEG_;
        __syncthreads();
        const int len = lens[b];
        int pp = 0;
        for (int tc = 0; tc < 16; ++tc) {
            if (tid == 0) {                            // gate: 32-t chunk ready
                int it = 0;
                while (__hip_atomic_load(fcnt + (tc >> 1), __ATOMIC_RELAXED,
                                         __HIP_MEMORY_SCOPE_AGENT) < 32) {
                    __builtin_amdgcn_s_sleep(16);
                    if (++it > (1 << 22)) break;       // bail -> visible failure, not hang
                }
            }
            __syncthreads();
            {   // coop-load 16-t chunk: thread = (batch bb, dt)
                const int bb = tid >> 4, dt = tid & 15;
                const int t = tc * 16 + dt;
                const float* src = feats + (size_t)(bb * 256 + t) * K_;
                f4_t v0, v1, v2;
                asm volatile("global_load_dwordx4 %0, %3, off sc0 sc1\n\t"
                             "global_load_dwordx4 %1, %4, off sc0 sc1\n\t"
                             "global_load_dwordx4 %2, %5, off sc0 sc1\n\t"
                             "s_waitcnt vmcnt(0)"
                             : "=v"(v0), "=v"(v1), "=v"(v2)
                             : "v"(src), "v"(src + 4), "v"(src + 8) : "memory");
                float* d = fbuf + (dt * 32 + bb) * 13;
                d[0] = v0.x; d[1] = v0.y; d[2]  = v0.z; d[3]  = v0.w;
                d[4] = v1.x; d[5] = v1.y; d[6]  = v1.z; d[7]  = v1.w;
                d[8] = v2.x; d[9] = v2.y; d[10] = v2.z; d[11] = v2.w;
            }
            __syncthreads();
            for (int dt = 0; dt < 16; ++dt) {
                const int t = tc * 16 + dt;
                if (lane < K_) {
                    float f_cur = fbuf[(dt * 32 + b) * 13 + lane];
                    float best = fv[pp * 512 + b * 16 + 0] + tl[lane * 16 + 0];
                    int argp = 0;
#pragma unroll
                    for (int p = 1; p < K_; ++p) {
                        float v = fv[pp * 512 + b * 16 + p] + tl[lane * 16 + p];
                        if (v > best) { best = v; argp = p; }   // strict > = first-max
                    }
                    float nb = best + f_cur;
                    fv[(pp ^ 1) * 512 + b * 16 + lane] =
                        (t < len) ? nb : fv[pp * 512 + b * 16 + lane];
                    int other = __shfl_xor(argp, 1);
                    if ((lane & 1) == 0)
                        bp[(t * 32 + b) * 6 + (lane >> 1)] = (unsigned char)(argp | (other << 4));
                }
                __syncthreads();
                pp ^= 1;
            }
        }
        if (lane == 0) {
            float best = fv[pp * 512 + b * 16 + 0] + tl[STOP_ * 16 + 0];
            int bl = 0;
#pragma unroll
            for (int p = 1; p < K_; ++p) {
                float v = fv[pp * 512 + b * 16 + p] + tl[STOP_ * 16 + p];
                if (v > best) { best = v; bl = p; }
            }
            out[b] = best;
            best_last[b] = bl;
        }
        __syncthreads();
        if (lane == 0) {                                // backtrace (overwrites gcnt/fcnt:
            int tag = best_last[b];                     // all their readers are done by now)
            for (int t = T_ - 1; t >= 0; --t) {
                int m = (t < len);
                out[B_ + b * T_ + t] = (float)(m ? tag : -1);
                if (m) tag = (bp[(t * 32 + b) * 6 + (tag >> 1)] >> ((tag & 1) * 4)) & 15;
            }
        }
        return;
    }

    if (blockIdx.x >= 1088) {
        // ================= feat role: 256 blocks x 32 positions =================
        const int blk = blockIdx.x - 1088;
        f4_t* hbuf = (f4_t*)smem;                // [32][129] f4 (pad kills bank conflicts)
#pragma unroll
        for (int i = 0; i < 8; ++i) {
            int idx = i * 512 + tid;             // 0..4095 = [pos 0..31][j 0..127]
            int pl = idx >> 7, j = idx & 127;
            int p = blk * 32 + pl;
            int b = p >> 8, t = p & 255;
            int len = lens[b];
            int g = b >> 3;
            int Tg = lens[g * 8];                // group Tmax (lens sorted desc)
            const float* addr;
            if (j < 64) {                        // fwd h at t
                addr = hex + ((size_t)g * T_ + t) * 2048 + (b & 7) * 256 + j * 4;
            } else {                             // bwd h at un-reversed index
                int tr = t < len ? len - 1 - t : t;
                addr = hex + ((size_t)(4 + g) * T_ + tr) * 2048 + (b & 7) * 256 + (j - 64) * 4;
            }
            float a0 = __hip_atomic_load(addr + 0, __ATOMIC_RELAXED, __HIP_MEMORY_SCOPE_AGENT);
            float a1 = __hip_atomic_load(addr + 1, __ATOMIC_RELAXED, __HIP_MEMORY_SCOPE_AGENT);
            float a2 = __hip_atomic_load(addr + 2, __ATOMIC_RELAXED, __HIP_MEMORY_SCOPE_AGENT);
            float a3 = __hip_atomic_load(addr + 3, __ATOMIC_RELAXED, __HIP_MEMORY_SCOPE_AGENT);
            if (t < Tg) {                        // real data coming: retry until non-magic
                int it = 0;
                while (__float_as_uint(a0) == MAGICU || __float_as_uint(a1) == MAGICU ||
                       __float_as_uint(a2) == MAGICU || __float_as_uint(a3) == MAGICU) {
                    __builtin_amdgcn_s_sleep(2);
                    a0 = __hip_atomic_load(addr + 0, __ATOMIC_RELAXED, __HIP_MEMORY_SCOPE_AGENT);
                    a1 = __hip_atomic_load(addr + 1, __ATOMIC_RELAXED, __HIP_MEMORY_SCOPE_AGENT);
                    a2 = __hip_atomic_load(addr + 2, __ATOMIC_RELAXED, __HIP_MEMORY_SCOPE_AGENT);
                    a3 = __hip_atomic_load(addr + 3, __ATOMIC_RELAXED, __HIP_MEMORY_SCOPE_AGENT);
                    if (++it > (1 << 22)) break; // bail -> visible failure, not hang
                }
            }
            f4_t v; v.x = a0; v.y = a1; v.z = a2; v.w = a3;
            hbuf[pl * 129 + j] = v;
        }
        __syncthreads();
        if (tid < 384) {
            int pl = tid / 12, k = tid - pl * 12;
            int p = blk * 32 + pl;
            const float4* w0 = (const float4*)(Wout + (size_t)k * 512);
            const f4_t* hrow = hbuf + pl * 129;
            float acc = bout[k];
#pragma unroll 4
            for (int j = 0; j < 128; ++j) {
                f4_t h4 = hrow[j];
                float4 v4 = w0[j];
                acc += h4.x * v4.x + h4.y * v4.y + h4.z * v4.z + h4.w * v4.w;
            }
            float* fdst = feats + (size_t)p * K_ + k;
            asm volatile("global_store_dword %0, %1, off sc0 sc1" :: "v"(fdst), "v"(acc) : "memory");
        }
        asm volatile("s_waitcnt vmcnt(0)" ::: "memory");
        __syncthreads();
        if (tid == 0)
            __hip_atomic_fetch_add(gcnt + 128 + (blk & 7), 1,
                                   __ATOMIC_RELEASE, __HIP_MEMORY_SCOPE_AGENT);
        return;
    }

    if (blockIdx.x >= 64) {
        // ================= in_gemm role (512 threads, 128x128 tile) =================
        const int bi = blockIdx.x - 64;
        const int by = bi >> 4, sub = bi & 15;   // by-major order -> early t-tiles first
        const int dir = sub >> 3, bx = sub & 7;
        const int n0 = bx * 128, m0 = by * 128;
        float* As = smem;                        // [8][128]
        float* Bs = smem + 1024;                 // [8][128]
        const int rs = (tid & 255) >> 1, kc = (tid & 1) * 4;
        const float* srow;
        if (tid < 256) {
            int tok = tokA[dir * 8192 + m0 + rs];
            srow = emb + (size_t)tok * E_;
        } else {
            int np = n0 + rs;
            int wrow = ((np & 3) << 8) | (np >> 2);   // permuted col n'=u*4+g -> Wih row g*256+u
            srow = (dir ? Wih_b : Wih_f) + (size_t)wrow * E_;
        }
        float* Ls = (tid < 256) ? As : Bs;
        const int ty = tid >> 4, tx = tid & 15;  // ty 0..31 (4 rows), tx 0..15 (8 cols)

        float acc[4][8];
#pragma unroll
        for (int i = 0; i < 4; ++i)
#pragma unroll
            for (int j = 0; j < 8; ++j) acc[i][j] = 0.f;

        for (int k0 = 0; k0 < E_; k0 += 8) {
            float4 v = *(const float4*)(srow + k0 + kc);
            __syncthreads();
            Ls[(kc + 0) * 128 + rs] = v.x;
            Ls[(kc + 1) * 128 + rs] = v.y;
            Ls[(kc + 2) * 128 + rs] = v.z;
            Ls[(kc + 3) * 128 + rs] = v.w;
            __syncthreads();
#pragma unroll
            for (int k = 0; k < 8; ++k) {
                float4 a  = *(const float4*)&As[k * 128 + ty * 4];
                float4 b0 = *(const float4*)&Bs[k * 128 + tx * 8];
                float4 b1 = *(const float4*)&Bs[k * 128 + tx * 8 + 4];
                float af[4] = {a.x, a.y, a.z, a.w};
                float bf[8] = {b0.x, b0.y, b0.z, b0.w, b1.x, b1.y, b1.z, b1.w};
#pragma unroll
                for (int i = 0; i < 4; ++i)
#pragma unroll
                    for (int j = 0; j < 8; ++j) acc[i][j] += af[i] * bf[j];
            }
        }
        const float* bihp = dir ? bih_b : bih_f;
        const float* bhhp = dir ? bhh_b : bhh_f;
        float bias[8];
#pragma unroll
        for (int j = 0; j < 8; ++j) {
            int nn = n0 + tx * 8 + j;
            int wr = ((nn & 3) << 8) | (nn >> 2);
            bias[j] = bihp[wr] + bhhp[wr];
        }
#pragma unroll
        for (int i = 0; i < 4; ++i) {
            int m = m0 + ty * 4 + i;
            float* gp = G + ((size_t)dir * 8192 + m) * NG_ + n0 + tx * 8;
            f4_t o0, o1;
            o0.x = acc[i][0] + bias[0]; o0.y = acc[i][1] + bias[1];
            o0.z = acc[i][2] + bias[2]; o0.w = acc[i][3] + bias[3];
            o1.x = acc[i][4] + bias[4]; o1.y = acc[i][5] + bias[5];
            o1.z = acc[i][6] + bias[6]; o1.w = acc[i][7] + bias[7];
            asm volatile("global_store_dwordx4 %0, %1, off sc0 sc1" :: "v"(gp), "v"(o0) : "memory");
            asm volatile("global_store_dwordx4 %0, %1, off sc0 sc1" :: "v"(gp + 4), "v"(o1) : "memory");
        }
        asm volatile("s_waitcnt vmcnt(0)" ::: "memory");
        __syncthreads();
        if (tid == 0)
            __hip_atomic_fetch_add(gcnt + dir * 64 + by, 1,
                                   __ATOMIC_RELEASE, __HIP_MEMORY_SCOPE_AGENT);
        return;
    }

    // ================= lstm role: v11 verbatim + G-counter gating =================
    float4* red4 = (float4*)smem;                // 512*11 f4 (90112 B)
    float4* hsA4 = (float4*)(smem + 22528);      // 256 f4: h[k][b0..3]
    float4* hsB4 = (float4*)(smem + 23552);      // 256 f4: h[k][b4..7]
    float4* hT4  = (float4*)(smem + 24576);      // 64 f4: own h [b][32u]

    const int wg = blockIdx.x;                   // dir*32 + bt*8 + ut
    const int dir = wg >> 5, bt = (wg >> 3) & 3, ut = wg & 7;
    const int wv = tid >> 6, ln = tid & 63;
    const int upair = ln & 15;
    const int kssub = ln >> 4;
    const int ksup = wv >> 1, bh = wv & 1;
    const int ks = ksup * 4 + kssub;
    const int sb = bh * 4 + (ln & 3);
    const int sk = ksup * 64 + (ln >> 2) * 4;
    const int speer = sk >> 5;

    const int Tmax = lens[bt * 8];               // lens sorted desc -> group max

    // ---- W into registers: 32 f4/thread ----
    const float4* WT4 = (const float4*)(WhhT + (size_t)dir * 256 * NG_);
    const int gu_e = ut * 32 + upair * 2;
    float4 We[16], Wo[16];
#pragma unroll
    for (int j = 0; j < 16; ++j) {
        We[j] = WT4[(ks * 16 + j) * 256 + gu_e];
        Wo[j] = WT4[(ks * 16 + j) * 256 + gu_e + 1];
    }

    // ---- wait for G tile by=0 (t=0..3) before the initial gp load ----
    {
        int it = 0;
        while (__hip_atomic_load(gcnt + dir * 64, __ATOMIC_RELAXED, __HIP_MEMORY_SCOPE_AGENT) < 8) {
            __builtin_amdgcn_s_sleep(8);
            if (++it > (1 << 22)) break;         // bail -> visible failure, not hang
        }
    }

    const bool is_act = (ln < 32);               // act lane: batch=wv, unit=ln
    float c = 0.f;
    float4 gpend = make_float4(0.f, 0.f, 0.f, 0.f);
    const float* Gd = G + (size_t)dir * 8192 * NG_;
    int gok = 1, gready = 0;                     // gp validity + highest known-ready by
    if (is_act) {
        c = c0[(dir * B_ + bt * 8 + wv) * HD_ + ut * 32 + ln];
        gpend = ((const float4*)(Gd + (size_t)(bt * 8 + wv) * NG_))[ut * 32 + ln];
    }

    float* hexg = hex + (size_t)(dir * 4 + bt) * T_ * 2048;  // [t][b*256+u]
    float4* hsX4 = bh ? hsB4 : hsA4;
    float* hsX = (float*)hsX4;

    f4_t pend;                                   // pre-issued poll data

    for (int t = 0; t < Tmax; ++t) {
        // ---- stage h(t-1) slice (wave-private region of hsX) ----
        float4 hv;
        if (t == 0) {
            hv = *(const float4*)(h0 + (size_t)(dir * B_ + bt * 8 + sb) * HD_ + sk);
        } else if (speer == ut) {
            hv = hT4[sb * 8 + ((sk & 31) >> 2)];         // own slice from LDS
        } else {
            asm volatile("s_waitcnt vmcnt(0)" ::: "memory");
            hv.x = pend.x; hv.y = pend.y; hv.z = pend.z; hv.w = pend.w;
            if (__float_as_uint(hv.x) == MAGICU || __float_as_uint(hv.y) == MAGICU ||
                __float_as_uint(hv.z) == MAGICU || __float_as_uint(hv.w) == MAGICU) {
                const float* src = hexg + (size_t)(t - 1) * 2048 + sb * 256 + sk;
                int it = 0;
                for (;;) {
                    __builtin_amdgcn_s_sleep(1);
                    float a0 = __hip_atomic_load(src + 0, __ATOMIC_RELAXED, __HIP_MEMORY_SCOPE_AGENT);
                    float a1 = __hip_atomic_load(src + 1, __ATOMIC_RELAXED, __HIP_MEMORY_SCOPE_AGENT);
                    float a2 = __hip_atomic_load(src + 2, __ATOMIC_RELAXED, __HIP_MEMORY_SCOPE_AGENT);
                    float a3 = __hip_atomic_load(src + 3, __ATOMIC_RELAXED, __HIP_MEMORY_SCOPE_AGENT);
                    if (!(__float_as_uint(a0) == MAGICU || __float_as_uint(a1) == MAGICU ||
                          __float_as_uint(a2) == MAGICU || __float_as_uint(a3) == MAGICU)) {
                        hv = make_float4(a0, a1, a2, a3); break;
                    }
                    if (++it > (1 << 22)) break;   // bail -> visible failure, not hang
                }
            }
        }
        // transpose into [k][4b-half] (wave-private rows)
        hsX[(sk + 0) * 4 + (ln & 3)] = hv.x;
        hsX[(sk + 1) * 4 + (ln & 3)] = hv.y;
        hsX[(sk + 2) * 4 + (ln & 3)] = hv.z;
        hsX[(sk + 3) * 4 + (ln & 3)] = hv.w;
        asm volatile("s_waitcnt lgkmcnt(0)" ::: "memory");   // wave-local visibility

        // ---- FMA: 2 units x 4 gates x 4 batches x 16 k, W in regs ----
        float4 ae0 = {0,0,0,0}, ae1 = {0,0,0,0}, ae2 = {0,0,0,0}, ae3 = {0,0,0,0};
        float4 ao0 = {0,0,0,0}, ao1 = {0,0,0,0}, ao2 = {0,0,0,0}, ao3 = {0,0,0,0};
#pragma unroll
        for (int j = 0; j < 16; ++j) {
            float4 h4 = hsX4[ks * 16 + j];        // h[k][4b of this half]
            float4 we = We[j], wo = Wo[j];
            ae0.x += we.x*h4.x; ae0.y += we.y*h4.x; ae0.z += we.z*h4.x; ae0.w += we.w*h4.x;
            ae1.x += we.x*h4.y; ae1.y += we.y*h4.y; ae1.z += we.z*h4.y; ae1.w += we.w*h4.y;
            ae2.x += we.x*h4.z; ae2.y += we.y*h4.z; ae2.z += we.z*h4.z; ae2.w += we.w*h4.z;
            ae3.x += we.x*h4.w; ae3.y += we.y*h4.w; ae3.z += we.z*h4.w; ae3.w += we.w*h4.w;
            ao0.x += wo.x*h4.x; ao0.y += wo.y*h4.x; ao0.z += wo.z*h4.x; ao0.w += wo.w*h4.x;
            ao1.x += wo.x*h4.y; ao1.y += wo.y*h4.y; ao1.z += wo.z*h4.y; ao1.w += wo.w*h4.y;
            ao2.x += wo.x*h4.z; ao2.y += wo.y*h4.z; ao2.z += wo.z*h4.z; ao2.w += wo.w*h4.z;
            ao3.x += wo.x*h4.w; ao3.y += wo.y*h4.w; ao3.z += wo.z*h4.w; ao3.w += wo.w*h4.w;
        }
        // ---- write partials: row = (wv*4+kssub)*16 + upair, slot = par*4 + b ----
        {
            float4* r = &red4[((wv * 4 + kssub) * 16 + upair) * 11 + kssub];
            r[0] = ae0; r[1] = ae1; r[2] = ae2; r[3] = ae3;
            r[4] = ao0; r[5] = ao1; r[6] = ao2; r[7] = ao3;
        }
        asm volatile("s_waitcnt lgkmcnt(0)\n\ts_barrier" ::: "memory");   // barrier 1

        // ---- act: lane<32 of wave wv handles (batch=wv, unit=ln) ----
        if (is_act) {
            const int b = wv, u = ln;
            const int bhv = b >> 2, bq = b & 3, up = u >> 1, par = u & 1;
            if (!gok) {                           // gp for this step not validated: poll + LLC reload
                const int byc = t >> 2;
                int itc = 0;
                while (__hip_atomic_load(gcnt + dir * 64 + byc, __ATOMIC_RELAXED,
                                         __HIP_MEMORY_SCOPE_AGENT) < 8) {
                    __builtin_amdgcn_s_sleep(2);
                    if (++itc > (1 << 22)) break;
                }
                const float* gsrc = Gd + ((size_t)t * B_ + bt * 8 + b) * NG_ + (size_t)(ut * 32 + u) * 4;
                f4_t tmp;
                asm volatile("global_load_dwordx4 %0, %1, off sc0 sc1\n\ts_waitcnt vmcnt(0)"
                             : "=v"(tmp) : "v"(gsrc) : "memory");
                gpend = make_float4(tmp.x, tmp.y, tmp.z, tmp.w);
            }
            float si = gpend.x, sf = gpend.y, sg = gpend.z, so = gpend.w;
#pragma unroll
            for (int kq = 0; kq < 4; ++kq)
#pragma unroll
                for (int kr = 0; kr < 4; ++kr) {
                    float4 p = red4[(((kq * 2 + bhv) * 4 + kr) * 16 + up) * 11 + kr + par * 4 + bq];
                    si += p.x; sf += p.y; sg += p.z; so += p.w;
                }
            c = sigf(sf) * c + sigf(si) * tanhf(sg);
            float h = sigf(so) * tanhf(c);
            ((float*)hT4)[b * 32 + u] = h;
            // publish: one contiguous 128B segment per wave, agent-coherent
            float* dst = hexg + (size_t)t * 2048 + b * 256 + ut * 32 + u;
            asm volatile("global_store_dword %0, %1, off sc0 sc1" :: "v"(dst), "v"(h) : "memory");
            if (t + 1 < Tmax) {                   // gated prefetch for t+1
                const int byn = (t + 1) >> 2;
                if (byn > gready) {
                    int la = byn + 7; if (la > 63) la = 63;
                    if (__hip_atomic_load(gcnt + dir * 64 + la, __ATOMIC_RELAXED,
                                          __HIP_MEMORY_SCOPE_AGENT) >= 8) gready = la;
                    else if (__hip_atomic_load(gcnt + dir * 64 + byn, __ATOMIC_RELAXED,
                                               __HIP_MEMORY_SCOPE_AGENT) >= 8) gready = byn;
                }
                if (byn <= gready) {
                    gpend = ((const float4*)(Gd + ((size_t)(t + 1) * B_ + bt * 8 + b) * NG_))[ut * 32 + u];
                    gok = 1;
                } else gok = 0;                   // skip -> no stale pull; reload next step
            }
        }
        // ---- pre-issue next step's poll (flight overlaps barrier + peer publish) ----
        if (t + 1 < Tmax && speer != ut) {
            const float* nsrc = hexg + (size_t)t * 2048 + sb * 256 + sk;
            asm volatile("global_load_dwordx4 %0, %1, off sc0 sc1"
                         : "=v"(pend) : "v"(nsrc) : "memory");
        }
        asm volatile("s_waitcnt lgkmcnt(0)\n\ts_barrier" ::: "memory");   // barrier 2
    }
}

extern "C" void kernel_launch(void* const* d_in, const int* in_sizes, int n_in,
                              void* d_out, int out_size, void* d_ws, size_t ws_size,
                              hipStream_t stream) {
    const int*   sent  = (const int*)d_in[0];
    const int*   lens  = (const int*)d_in[1];
    const float* emb   = (const float*)d_in[2];
    const float* Wih_f = (const float*)d_in[3];
    const float* Whh_f = (const float*)d_in[4];
    const float* bih_f = (const float*)d_in[5];
    const float* bhh_f = (const float*)d_in[6];
    const float* Wih_b = (const float*)d_in[7];
    const float* Whh_b = (const float*)d_in[8];
    const float* bih_b = (const float*)d_in[9];
    const float* bhh_b = (const float*)d_in[10];
    const float* h0    = (const float*)d_in[11];
    const float* c0    = (const float*)d_in[12];
    const float* Wout  = (const float*)d_in[13];
    const float* bout  = (const float*)d_in[14];
    const float* trans = (const float*)d_in[15];
    float* out = (float*)d_out;

    char* ws = (char*)d_ws;
    int*   tokA  = (int*)ws;                                  // 64 KB
    float* WhhT  = (float*)(ws + 65536);                      // 2 MB
    float* G     = (float*)(ws + 2162688);                    // 67.1 MB
    float* feats = (float*)(ws + 69271552);                   // 0.39 MB
    float* hex   = (float*)(ws + 69664768);                   // 16 MB  [8 groups][T][2048]
    // gcnt: 128 ints + fcnt: 8 ints in d_out's preds region (out[32..168));
    // zeroed by prep, overwritten only by viterbi's backtrace after all
    // gcnt/fcnt readers are provably done.
    int*   gcnt  = (int*)(out + 32);

    prep<<<4672, 256, 0, stream>>>(sent, lens, tokA, Whh_f, Whh_b, WhhT, hex, gcnt);
    mega<<<1345, 512, 0, stream>>>(emb, tokA, Wih_f, Wih_b, bih_f, bhh_f, bih_b, bhh_b,
                                   WhhT, G, h0, c0, lens, hex, gcnt, Wout, bout, feats,
                                   trans, out);
}

// Round 11
// 1066.063 us; speedup vs baseline: 1.1189x; 1.1189x over previous
//
#include <hip/hip_runtime.h>
#include <math.h>

#define T_ 256
#define B_ 32
#define E_ 256
#define HD_ 256
#define NG_ 1024
#define K_ 12
#define START_ 10
#define STOP_ 11
#define NEG_ -10000.0f
#define MAGICU 0x40000000u   // 2.0f — |h|<1 so h can never be this bit pattern

typedef float f4_t __attribute__((ext_vector_type(4)));

__device__ __forceinline__ float sigf(float x) { return 1.0f / (1.0f + expf(-x)); }

// ---------- fused prep: hex sentinel fill + Whh^T + token gather + gcnt zero ----------
__global__ void prep(const int* __restrict__ sent, const int* __restrict__ lens,
                     int* __restrict__ tokA, const float* __restrict__ Wf,
                     const float* __restrict__ Wb, float* __restrict__ WT,
                     float* __restrict__ hex, int* __restrict__ gcnt) {
    const int b = blockIdx.x, tid = threadIdx.x;
    if (b < 4096) {
        // hex sentinel fill: 4096 blocks x 256 thr x 16 B = 16 MB
        float4 m = make_float4(2.0f, 2.0f, 2.0f, 2.0f);
        ((float4*)hex)[b * 256 + tid] = m;
        if (b == 0 && tid < 128) gcnt[tid] = 0;   // gcnt lives in d_out preds region
    } else if (b < 4608) {
        // Whh^T into [dir][k][u*4+gate] (unit-major gate packing)
        int b2 = b - 4096;
        int dir = b2 >> 8, k = b2 & 255, u = tid;
        const float* W = dir ? Wb : Wf;
        float4 v;
        v.x = W[(0 * HD_ + u) * HD_ + k];   // i
        v.y = W[(1 * HD_ + u) * HD_ + k];   // f
        v.z = W[(2 * HD_ + u) * HD_ + k];   // g
        v.w = W[(3 * HD_ + u) * HD_ + k];   // o
        ((float4*)(WT + ((size_t)dir * 256 + k) * NG_))[u] = v;
    } else {
        // token gather (bwd dir reversed within each sequence length)
        int e = (b - 4608) * 256 + tid;      // 0..16383 = [dir][t*32+b]
        int dir = e >> 13, m = e & 8191, t = m >> 5, bb = m & 31;
        int len = lens[bb];
        int tt = dir ? (t < len ? len - 1 - t : t) : t;
        tokA[e] = sent[bb * T_ + tt];
    }
}

// ---------- mega-kernel, 3 roles by blockIdx (r8 protocol, r10 viterbi-fusion
// reverted). ONE delta vs r8: the lstm act reduction now uses ALL 64 lanes
// (each lane sums 8 of 16 partials for (b=wv, u=ln&31); shfl_xor(32) combines)
// — halves the serial LDS-add depth on the publish critical path.
//   [0,64)      v11 lstm recurrence (proven exchange, gcnt-gated G prefetch)
//   [64,1088)   in_gemm producers: sc0 sc1 write-through G stores + vmcnt(0)
//               drain + barrier + atomicAdd release (r6-proven)
//   [1088,1344) feat blocks: RELAXED agent atomic polls of hex with sleep+bail
//               (the identical h-exchange idiom); skip retry for t >= Tmax_group
// All spins carry bail counters -> no hang possible.
__global__ __launch_bounds__(512, 1) void mega(
    const float* __restrict__ emb, const int* __restrict__ tokA,
    const float* __restrict__ Wih_f, const float* __restrict__ Wih_b,
    const float* __restrict__ bih_f, const float* __restrict__ bhh_f,
    const float* __restrict__ bih_b, const float* __restrict__ bhh_b,
    const float* __restrict__ WhhT, float* __restrict__ G,
    const float* __restrict__ h0, const float* __restrict__ c0,
    const int* __restrict__ lens, float* __restrict__ hex,
    int* __restrict__ gcnt, const float* __restrict__ Wout,
    const float* __restrict__ bout, float* __restrict__ feats) {
    __shared__ float smem[24832];                // 99328 B, carved per role
    const int tid = threadIdx.x;

    if (blockIdx.x >= 1088) {
        // ================= feat role: 256 blocks x 32 positions =================
        const int blk = blockIdx.x - 1088;
        f4_t* hbuf = (f4_t*)smem;                // [32][129] f4 (pad kills bank conflicts)
#pragma unroll
        for (int i = 0; i < 8; ++i) {
            int idx = i * 512 + tid;             // 0..4095 = [pos 0..31][j 0..127]
            int pl = idx >> 7, j = idx & 127;
            int p = blk * 32 + pl;
            int b = p >> 8, t = p & 255;
            int len = lens[b];
            int g = b >> 3;
            int Tg = lens[g * 8];                // group Tmax (lens sorted desc)
            const float* addr;
            if (j < 64) {                        // fwd h at t
                addr = hex + ((size_t)g * T_ + t) * 2048 + (b & 7) * 256 + j * 4;
            } else {                             // bwd h at un-reversed index
                int tr = t < len ? len - 1 - t : t;
                addr = hex + ((size_t)(4 + g) * T_ + tr) * 2048 + (b & 7) * 256 + (j - 64) * 4;
            }
            float a0 = __hip_atomic_load(addr + 0, __ATOMIC_RELAXED, __HIP_MEMORY_SCOPE_AGENT);
            float a1 = __hip_atomic_load(addr + 1, __ATOMIC_RELAXED, __HIP_MEMORY_SCOPE_AGENT);
            float a2 = __hip_atomic_load(addr + 2, __ATOMIC_RELAXED, __HIP_MEMORY_SCOPE_AGENT);
            float a3 = __hip_atomic_load(addr + 3, __ATOMIC_RELAXED, __HIP_MEMORY_SCOPE_AGENT);
            if (t < Tg) {                        // real data coming: retry until non-magic
                int it = 0;
                while (__float_as_uint(a0) == MAGICU || __float_as_uint(a1) == MAGICU ||
                       __float_as_uint(a2) == MAGICU || __float_as_uint(a3) == MAGICU) {
                    __builtin_amdgcn_s_sleep(2);
                    a0 = __hip_atomic_load(addr + 0, __ATOMIC_RELAXED, __HIP_MEMORY_SCOPE_AGENT);
                    a1 = __hip_atomic_load(addr + 1, __ATOMIC_RELAXED, __HIP_MEMORY_SCOPE_AGENT);
                    a2 = __hip_atomic_load(addr + 2, __ATOMIC_RELAXED, __HIP_MEMORY_SCOPE_AGENT);
                    a3 = __hip_atomic_load(addr + 3, __ATOMIC_RELAXED, __HIP_MEMORY_SCOPE_AGENT);
                    if (++it > (1 << 22)) break; // bail -> visible failure, not hang
                }
            }
            f4_t v; v.x = a0; v.y = a1; v.z = a2; v.w = a3;
            hbuf[pl * 129 + j] = v;
        }
        __syncthreads();
        if (tid < 384) {
            int pl = tid / 12, k = tid - pl * 12;
            int p = blk * 32 + pl;
            const float4* w0 = (const float4*)(Wout + (size_t)k * 512);
            const f4_t* hrow = hbuf + pl * 129;
            float acc = bout[k];
#pragma unroll 4
            for (int j = 0; j < 128; ++j) {
                f4_t h4 = hrow[j];
                float4 v4 = w0[j];
                acc += h4.x * v4.x + h4.y * v4.y + h4.z * v4.z + h4.w * v4.w;
            }
            feats[(size_t)p * K_ + k] = acc;
        }
        return;
    }

    if (blockIdx.x >= 64) {
        // ================= in_gemm role (512 threads, 128x128 tile) =================
        const int bi = blockIdx.x - 64;
        const int by = bi >> 4, sub = bi & 15;   // by-major order -> early t-tiles first
        const int dir = sub >> 3, bx = sub & 7;
        const int n0 = bx * 128, m0 = by * 128;
        float* As = smem;                        // [8][128]
        float* Bs = smem + 1024;                 // [8][128]
        const int rs = (tid & 255) >> 1, kc = (tid & 1) * 4;
        const float* srow;
        if (tid < 256) {
            int tok = tokA[dir * 8192 + m0 + rs];
            srow = emb + (size_t)tok * E_;
        } else {
            int np = n0 + rs;
            int wrow = ((np & 3) << 8) | (np >> 2);   // permuted col n'=u*4+g -> Wih row g*256+u
            srow = (dir ? Wih_b : Wih_f) + (size_t)wrow * E_;
        }
        float* Ls = (tid < 256) ? As : Bs;
        const int ty = tid >> 4, tx = tid & 15;  // ty 0..31 (4 rows), tx 0..15 (8 cols)

        float acc[4][8];
#pragma unroll
        for (int i = 0; i < 4; ++i)
#pragma unroll
            for (int j = 0; j < 8; ++j) acc[i][j] = 0.f;

        for (int k0 = 0; k0 < E_; k0 += 8) {
            float4 v = *(const float4*)(srow + k0 + kc);
            __syncthreads();
            Ls[(kc + 0) * 128 + rs] = v.x;
            Ls[(kc + 1) * 128 + rs] = v.y;
            Ls[(kc + 2) * 128 + rs] = v.z;
            Ls[(kc + 3) * 128 + rs] = v.w;
            __syncthreads();
#pragma unroll
            for (int k = 0; k < 8; ++k) {
                float4 a  = *(const float4*)&As[k * 128 + ty * 4];
                float4 b0 = *(const float4*)&Bs[k * 128 + tx * 8];
                float4 b1 = *(const float4*)&Bs[k * 128 + tx * 8 + 4];
                float af[4] = {a.x, a.y, a.z, a.w};
                float bf[8] = {b0.x, b0.y, b0.z, b0.w, b1.x, b1.y, b1.z, b1.w};
#pragma unroll
                for (int i = 0; i < 4; ++i)
#pragma unroll
                    for (int j = 0; j < 8; ++j) acc[i][j] += af[i] * bf[j];
            }
        }
        const float* bihp = dir ? bih_b : bih_f;
        const float* bhhp = dir ? bhh_b : bhh_f;
        float bias[8];
#pragma unroll
        for (int j = 0; j < 8; ++j) {
            int nn = n0 + tx * 8 + j;
            int wr = ((nn & 3) << 8) | (nn >> 2);
            bias[j] = bihp[wr] + bhhp[wr];
        }
#pragma unroll
        for (int i = 0; i < 4; ++i) {
            int m = m0 + ty * 4 + i;
            float* gp = G + ((size_t)dir * 8192 + m) * NG_ + n0 + tx * 8;
            f4_t o0, o1;
            o0.x = acc[i][0] + bias[0]; o0.y = acc[i][1] + bias[1];
            o0.z = acc[i][2] + bias[2]; o0.w = acc[i][3] + bias[3];
            o1.x = acc[i][4] + bias[4]; o1.y = acc[i][5] + bias[5];
            o1.z = acc[i][6] + bias[6]; o1.w = acc[i][7] + bias[7];
            asm volatile("global_store_dwordx4 %0, %1, off sc0 sc1" :: "v"(gp), "v"(o0) : "memory");
            asm volatile("global_store_dwordx4 %0, %1, off sc0 sc1" :: "v"(gp + 4), "v"(o1) : "memory");
        }
        asm volatile("s_waitcnt vmcnt(0)" ::: "memory");
        __syncthreads();
        if (tid == 0)
            __hip_atomic_fetch_add(gcnt + dir * 64 + by, 1,
                                   __ATOMIC_RELEASE, __HIP_MEMORY_SCOPE_AGENT);
        return;
    }

    // ================= lstm role: v11 + 64-lane act reduction =================
    float4* red4 = (float4*)smem;                // 512*11 f4 (90112 B)
    float4* hsA4 = (float4*)(smem + 22528);      // 256 f4: h[k][b0..3]
    float4* hsB4 = (float4*)(smem + 23552);      // 256 f4: h[k][b4..7]
    float4* hT4  = (float4*)(smem + 24576);      // 64 f4: own h [b][32u]

    const int wg = blockIdx.x;                   // dir*32 + bt*8 + ut
    const int dir = wg >> 5, bt = (wg >> 3) & 3, ut = wg & 7;
    const int wv = tid >> 6, ln = tid & 63;
    const int upair = ln & 15;
    const int kssub = ln >> 4;
    const int ksup = wv >> 1, bh = wv & 1;
    const int ks = ksup * 4 + kssub;
    const int sb = bh * 4 + (ln & 3);
    const int sk = ksup * 64 + (ln >> 2) * 4;
    const int speer = sk >> 5;

    const int Tmax = lens[bt * 8];               // lens sorted desc -> group max

    // ---- W into registers: 32 f4/thread ----
    const float4* WT4 = (const float4*)(WhhT + (size_t)dir * 256 * NG_);
    const int gu_e = ut * 32 + upair * 2;
    float4 We[16], Wo[16];
#pragma unroll
    for (int j = 0; j < 16; ++j) {
        We[j] = WT4[(ks * 16 + j) * 256 + gu_e];
        Wo[j] = WT4[(ks * 16 + j) * 256 + gu_e + 1];
    }

    // ---- wait for G tile by=0 (t=0..3) before the initial gp load ----
    {
        int it = 0;
        while (__hip_atomic_load(gcnt + dir * 64, __ATOMIC_RELAXED, __HIP_MEMORY_SCOPE_AGENT) < 8) {
            __builtin_amdgcn_s_sleep(8);
            if (++it > (1 << 22)) break;         // bail -> visible failure, not hang
        }
    }

    const bool is_act = (ln < 32);               // act lane: batch=wv, unit=ln
    float c = 0.f;
    float4 gpend = make_float4(0.f, 0.f, 0.f, 0.f);
    const float* Gd = G + (size_t)dir * 8192 * NG_;
    int gok = 1, gready = 0;                     // gp validity + highest known-ready by
    if (is_act) {
        c = c0[(dir * B_ + bt * 8 + wv) * HD_ + ut * 32 + ln];
        gpend = ((const float4*)(Gd + (size_t)(bt * 8 + wv) * NG_))[ut * 32 + ln];
    }

    float* hexg = hex + (size_t)(dir * 4 + bt) * T_ * 2048;  // [t][b*256+u]
    float4* hsX4 = bh ? hsB4 : hsA4;
    float* hsX = (float*)hsX4;

    f4_t pend;                                   // pre-issued poll data

    for (int t = 0; t < Tmax; ++t) {
        // ---- stage h(t-1) slice (wave-private region of hsX) ----
        float4 hv;
        if (t == 0) {
            hv = *(const float4*)(h0 + (size_t)(dir * B_ + bt * 8 + sb) * HD_ + sk);
        } else if (speer == ut) {
            hv = hT4[sb * 8 + ((sk & 31) >> 2)];         // own slice from LDS
        } else {
            asm volatile("s_waitcnt vmcnt(0)" ::: "memory");
            hv.x = pend.x; hv.y = pend.y; hv.z = pend.z; hv.w = pend.w;
            if (__float_as_uint(hv.x) == MAGICU || __float_as_uint(hv.y) == MAGICU ||
                __float_as_uint(hv.z) == MAGICU || __float_as_uint(hv.w) == MAGICU) {
                const float* src = hexg + (size_t)(t - 1) * 2048 + sb * 256 + sk;
                int it = 0;
                for (;;) {
                    __builtin_amdgcn_s_sleep(1);
                    float a0 = __hip_atomic_load(src + 0, __ATOMIC_RELAXED, __HIP_MEMORY_SCOPE_AGENT);
                    float a1 = __hip_atomic_load(src + 1, __ATOMIC_RELAXED, __HIP_MEMORY_SCOPE_AGENT);
                    float a2 = __hip_atomic_load(src + 2, __ATOMIC_RELAXED, __HIP_MEMORY_SCOPE_AGENT);
                    float a3 = __hip_atomic_load(src + 3, __ATOMIC_RELAXED, __HIP_MEMORY_SCOPE_AGENT);
                    if (!(__float_as_uint(a0) == MAGICU || __float_as_uint(a1) == MAGICU ||
                          __float_as_uint(a2) == MAGICU || __float_as_uint(a3) == MAGICU)) {
                        hv = make_float4(a0, a1, a2, a3); break;
                    }
                    if (++it > (1 << 22)) break;   // bail -> visible failure, not hang
                }
            }
        }
        // transpose into [k][4b-half] (wave-private rows)
        hsX[(sk + 0) * 4 + (ln & 3)] = hv.x;
        hsX[(sk + 1) * 4 + (ln & 3)] = hv.y;
        hsX[(sk + 2) * 4 + (ln & 3)] = hv.z;
        hsX[(sk + 3) * 4 + (ln & 3)] = hv.w;
        asm volatile("s_waitcnt lgkmcnt(0)" ::: "memory");   // wave-local visibility

        // ---- FMA: 2 units x 4 gates x 4 batches x 16 k, W in regs ----
        float4 ae0 = {0,0,0,0}, ae1 = {0,0,0,0}, ae2 = {0,0,0,0}, ae3 = {0,0,0,0};
        float4 ao0 = {0,0,0,0}, ao1 = {0,0,0,0}, ao2 = {0,0,0,0}, ao3 = {0,0,0,0};
#pragma unroll
        for (int j = 0; j < 16; ++j) {
            float4 h4 = hsX4[ks * 16 + j];        // h[k][4b of this half]
            float4 we = We[j], wo = Wo[j];
            ae0.x += we.x*h4.x; ae0.y += we.y*h4.x; ae0.z += we.z*h4.x; ae0.w += we.w*h4.x;
            ae1.x += we.x*h4.y; ae1.y += we.y*h4.y; ae1.z += we.z*h4.y; ae1.w += we.w*h4.y;
            ae2.x += we.x*h4.z; ae2.y += we.y*h4.z; ae2.z += we.z*h4.z; ae2.w += we.w*h4.z;
            ae3.x += we.x*h4.w; ae3.y += we.y*h4.w; ae3.z += we.z*h4.w; ae3.w += we.w*h4.w;
            ao0.x += wo.x*h4.x; ao0.y += wo.y*h4.x; ao0.z += wo.z*h4.x; ao0.w += wo.w*h4.x;
            ao1.x += wo.x*h4.y; ao1.y += wo.y*h4.y; ao1.z += wo.z*h4.y; ao1.w += wo.w*h4.y;
            ao2.x += wo.x*h4.z; ao2.y += wo.y*h4.z; ao2.z += wo.z*h4.z; ao2.w += wo.w*h4.z;
            ao3.x += wo.x*h4.w; ao3.y += wo.y*h4.w; ao3.z += wo.z*h4.w; ao3.w += wo.w*h4.w;
        }
        // ---- write partials: row = (wv*4+kssub)*16 + upair, slot = par*4 + b ----
        {
            float4* r = &red4[((wv * 4 + kssub) * 16 + upair) * 11 + kssub];
            r[0] = ae0; r[1] = ae1; r[2] = ae2; r[3] = ae3;
            r[4] = ao0; r[5] = ao1; r[6] = ao2; r[7] = ao3;
        }
        asm volatile("s_waitcnt lgkmcnt(0)\n\ts_barrier" ::: "memory");   // barrier 1

        // ---- act reduction: ALL 64 lanes. Lane ln handles (b=wv, u=ln&31);
        // half = ln>>5 sums kq in {2h, 2h+1} (8 of 16 partials); shfl_xor(32)
        // combines the halves into the act lanes (ln<32). Halves the serial
        // LDS-add depth on the publish critical path vs the 32-lane version.
        {
            const int b = wv, u = ln & 31, half = ln >> 5;
            const int bhv = b >> 2, bq = b & 3, up = u >> 1, par = u & 1;
            float rx = 0.f, ry = 0.f, rz = 0.f, rw = 0.f;
#pragma unroll
            for (int kq2 = 0; kq2 < 2; ++kq2) {
                const int kq = half * 2 + kq2;
#pragma unroll
                for (int kr = 0; kr < 4; ++kr) {
                    float4 p = red4[(((kq * 2 + bhv) * 4 + kr) * 16 + up) * 11 + kr + par * 4 + bq];
                    rx += p.x; ry += p.y; rz += p.z; rw += p.w;
                }
            }
            float ox = __shfl_xor(rx, 32);
            float oy = __shfl_xor(ry, 32);
            float oz = __shfl_xor(rz, 32);
            float ow = __shfl_xor(rw, 32);
            if (is_act) {
                if (!gok) {                       // gp for this step not validated: poll + LLC reload
                    const int byc = t >> 2;
                    int itc = 0;
                    while (__hip_atomic_load(gcnt + dir * 64 + byc, __ATOMIC_RELAXED,
                                             __HIP_MEMORY_SCOPE_AGENT) < 8) {
                        __builtin_amdgcn_s_sleep(2);
                        if (++itc > (1 << 22)) break;
                    }
                    const float* gsrc = Gd + ((size_t)t * B_ + bt * 8 + b) * NG_ + (size_t)(ut * 32 + u) * 4;
                    f4_t tmp;
                    asm volatile("global_load_dwordx4 %0, %1, off sc0 sc1\n\ts_waitcnt vmcnt(0)"
                                 : "=v"(tmp) : "v"(gsrc) : "memory");
                    gpend = make_float4(tmp.x, tmp.y, tmp.z, tmp.w);
                }
                float si = gpend.x + rx + ox;
                float sf = gpend.y + ry + oy;
                float sg = gpend.z + rz + oz;
                float so = gpend.w + rw + ow;
                c = sigf(sf) * c + sigf(si) * tanhf(sg);
                float h = sigf(so) * tanhf(c);
                ((float*)hT4)[b * 32 + u] = h;
                // publish: one contiguous 128B segment per wave, agent-coherent
                float* dst = hexg + (size_t)t * 2048 + b * 256 + ut * 32 + u;
                asm volatile("global_store_dword %0, %1, off sc0 sc1" :: "v"(dst), "v"(h) : "memory");
                if (t + 1 < Tmax) {               // gated prefetch for t+1
                    const int byn = (t + 1) >> 2;
                    if (byn > gready) {
                        int la = byn + 7; if (la > 63) la = 63;
                        if (__hip_atomic_load(gcnt + dir * 64 + la, __ATOMIC_RELAXED,
                                              __HIP_MEMORY_SCOPE_AGENT) >= 8) gready = la;
                        else if (__hip_atomic_load(gcnt + dir * 64 + byn, __ATOMIC_RELAXED,
                                                   __HIP_MEMORY_SCOPE_AGENT) >= 8) gready = byn;
                    }
                    if (byn <= gready) {
                        gpend = ((const float4*)(Gd + ((size_t)(t + 1) * B_ + bt * 8 + b) * NG_))[ut * 32 + u];
                        gok = 1;
                    } else gok = 0;               // skip -> no stale pull; reload next step
                }
            }
        }
        // ---- pre-issue next step's poll (flight overlaps barrier + peer publish) ----
        if (t + 1 < Tmax && speer != ut) {
            const float* nsrc = hexg + (size_t)t * 2048 + sb * 256 + sk;
            asm volatile("global_load_dwordx4 %0, %1, off sc0 sc1"
                         : "=v"(pend) : "v"(nsrc) : "memory");
        }
        asm volatile("s_waitcnt lgkmcnt(0)\n\ts_barrier" ::: "memory");   // barrier 2
    }
}

// ---------- Viterbi + backtrace: single block, feats prefetch, bp nibble-packed ----------
__global__ __launch_bounds__(512) void viterbi_k(
    const float* __restrict__ feats, const float* __restrict__ trans,
    const int* __restrict__ lens, float* __restrict__ out) {
    __shared__ float fv[2][B_][16];
    __shared__ float tl[K_][16];
    __shared__ unsigned char bp[T_][B_][6];    // 4-bit backpointers, 48KB
    __shared__ int best_last[B_];
    int tid = threadIdx.x;
    int b = tid >> 4, lane = tid & 15;
    if (tid < K_ * K_) tl[tid / 12][tid % 12] = trans[tid];
    if (lane < K_) fv[0][b][lane] = (lane == START_) ? 0.f : NEG_;
    __syncthreads();
    int len = lens[b];
    int pp = 0;
    float f_cur = 0.f;
    if (lane < K_) f_cur = feats[(size_t)b * T_ * K_ + lane];
    for (int t = 0; t < T_; ++t) {
        float f_nxt = 0.f;                       // prefetch t+1 before the compute chain
        if (t + 1 < T_ && lane < K_) f_nxt = feats[((size_t)b * T_ + t + 1) * K_ + lane];
        if (lane < K_) {
            float best = fv[pp][b][0] + tl[lane][0];
            int argp = 0;
#pragma unroll
            for (int p = 1; p < K_; ++p) {
                float v = fv[pp][b][p] + tl[lane][p];
                if (v > best) { best = v; argp = p; }   // strict > = first-max (matches jnp.argmax)
            }
            float nb = best + f_cur;
            fv[pp ^ 1][b][lane] = (t < len) ? nb : fv[pp][b][lane];
            int other = __shfl_xor(argp, 1);
            if ((lane & 1) == 0) bp[t][b][lane >> 1] = (unsigned char)(argp | (other << 4));
        }
        __syncthreads();
        pp ^= 1;
        f_cur = f_nxt;
    }
    if (lane == 0) {
        float best = fv[pp][b][0] + tl[STOP_][0];
        int bl = 0;
#pragma unroll
        for (int p = 1; p < K_; ++p) {
            float v = fv[pp][b][p] + tl[STOP_][p];
            if (v > best) { best = v; bl = p; }
        }
        out[b] = best;
        best_last[b] = bl;
    }
    __syncthreads();
    if (lane == 0) {
        int tag = best_last[b];
        for (int t = T_ - 1; t >= 0; --t) {
            int m = (t < len);
            out[B_ + b * T_ + t] = (float)(m ? tag : -1);
            if (m) tag = (bp[t][b][tag >> 1] >> ((tag & 1) * 4)) & 15;
        }
    }
}

extern "C" void kernel_launch(void* const* d_in, const int* in_sizes, int n_in,
                              void* d_out, int out_size, void* d_ws, size_t ws_size,
                              hipStream_t stream) {
    const int*   sent  = (const int*)d_in[0];
    const int*   lens  = (const int*)d_in[1];
    const float* emb   = (const float*)d_in[2];
    const float* Wih_f = (const float*)d_in[3];
    const float* Whh_f = (const float*)d_in[4];
    const float* bih_f = (const float*)d_in[5];
    const float* bhh_f = (const float*)d_in[6];
    const float* Wih_b = (const float*)d_in[7];
    const float* Whh_b = (const float*)d_in[8];
    const float* bih_b = (const float*)d_in[9];
    const float* bhh_b = (const float*)d_in[10];
    const float* h0    = (const float*)d_in[11];
    const float* c0    = (const float*)d_in[12];
    const float* Wout  = (const float*)d_in[13];
    const float* bout  = (const float*)d_in[14];
    const float* trans = (const float*)d_in[15];
    float* out = (float*)d_out;

    char* ws = (char*)d_ws;
    int*   tokA  = (int*)ws;                                  // 64 KB
    float* WhhT  = (float*)(ws + 65536);                      // 2 MB
    float* G     = (float*)(ws + 2162688);                    // 67.1 MB
    float* feats = (float*)(ws + 69271552);                   // 0.39 MB
    float* hex   = (float*)(ws + 69664768);                   // 16 MB  [8 groups][T][2048]
    // gcnt: 128 ints in d_out's preds region (out[32..159]); zeroed by prep,
    // fully overwritten by viterbi_k at the end. feats region is written
    // concurrently by the feat role, so an overlay there would race.
    int*   gcnt  = (int*)(out + 32);

    prep<<<4672, 256, 0, stream>>>(sent, lens, tokA, Whh_f, Whh_b, WhhT, hex, gcnt);
    mega<<<1344, 512, 0, stream>>>(emb, tokA, Wih_f, Wih_b, bih_f, bhh_f, bih_b, bhh_b,
                                   WhhT, G, h0, c0, lens, hex, gcnt, Wout, bout, feats);
    viterbi_k<<<1, 512, 0, stream>>>(feats, trans, lens, out);
}

// Round 12
// 1058.667 us; speedup vs baseline: 1.1267x; 1.0070x over previous
//
#include <hip/hip_runtime.h>
#include <math.h>

#define T_ 256
#define B_ 32
#define E_ 256
#define HD_ 256
#define NG_ 1024
#define K_ 12
#define START_ 10
#define STOP_ 11
#define NEG_ -10000.0f
#define MAGICU 0x40000000u   // 2.0f — |h|<1 so h can never be this bit pattern

typedef float f4_t __attribute__((ext_vector_type(4)));

__device__ __forceinline__ float sigf(float x) { return 1.0f / (1.0f + expf(-x)); }

// ---------- fused prep: hex sentinel fill + Whh^T + token gather + gcnt zero ----------
__global__ void prep(const int* __restrict__ sent, const int* __restrict__ lens,
                     int* __restrict__ tokA, const float* __restrict__ Wf,
                     const float* __restrict__ Wb, float* __restrict__ WT,
                     float* __restrict__ hex, int* __restrict__ gcnt) {
    const int b = blockIdx.x, tid = threadIdx.x;
    if (b < 4096) {
        // hex sentinel fill — only rows t < Tmax(group) are ever retry-polled:
        // lstm touches rows [0,Tmax); feat retries only for t < Tg. Rows >= Tmax
        // feed positions masked downstream (t >= Tg >= len) -> skip their fill.
        int i = b * 256 + tid;                   // f4 index into hex (1M total)
        int t = (i & 131071) >> 9;               // row within group (512 f4/row)
        int bt = (i >> 17) & 3;                  // bt within dir
        if (t < lens[bt * 8]) {
            float4 m = make_float4(2.0f, 2.0f, 2.0f, 2.0f);
            ((float4*)hex)[i] = m;
        }
        if (b == 0 && tid < 128) gcnt[tid] = 0;  // gcnt lives in d_out preds region
    } else if (b < 4608) {
        // Whh^T into [dir][k][u*4+gate] (unit-major gate packing)
        int b2 = b - 4096;
        int dir = b2 >> 8, k = b2 & 255, u = tid;
        const float* W = dir ? Wb : Wf;
        float4 v;
        v.x = W[(0 * HD_ + u) * HD_ + k];   // i
        v.y = W[(1 * HD_ + u) * HD_ + k];   // f
        v.z = W[(2 * HD_ + u) * HD_ + k];   // g
        v.w = W[(3 * HD_ + u) * HD_ + k];   // o
        ((float4*)(WT + ((size_t)dir * 256 + k) * NG_))[u] = v;
    } else {
        // token gather (bwd dir reversed within each sequence length)
        int e = (b - 4608) * 256 + tid;      // 0..16383 = [dir][t*32+b]
        int dir = e >> 13, m = e & 8191, t = m >> 5, bb = m & 31;
        int len = lens[bb];
        int tt = dir ? (t < len ? len - 1 - t : t) : t;
        tokA[e] = sent[bb * T_ + tt];
    }
}

// ---------- mega-kernel, 3 roles by blockIdx (r11 structure; poll hygiene):
//   [0,64)      v11 lstm + 64-lane act reduction. Fallback poll is loads-FIRST
//               (RELAXED agent atomics — the proven primitive), sleep only after
//               a confirmed fresh miss (pend's miss info is ~300cy stale).
//   [64,1088)   in_gemm producers: sc0 sc1 write-through G stores + vmcnt(0)
//               drain + barrier + atomicAdd release (r6-proven)
//   [1088,1344) feat blocks: loads-first RELAXED agent polls with sleep(16)
//               backoff (~10x less LLC poll traffic than r8's sleep(2); the
//               traffic measurably degraded the lstm exchange: r6->r8 +23us)
// All spins carry bail counters -> no hang possible.
__global__ __launch_bounds__(512, 1) void mega(
    const float* __restrict__ emb, const int* __restrict__ tokA,
    const float* __restrict__ Wih_f, const float* __restrict__ Wih_b,
    const float* __restrict__ bih_f, const float* __restrict__ bhh_f,
    const float* __restrict__ bih_b, const float* __restrict__ bhh_b,
    const float* __restrict__ WhhT, float* __restrict__ G,
    const float* __restrict__ h0, const float* __restrict__ c0,
    const int* __restrict__ lens, float* __restrict__ hex,
    int* __restrict__ gcnt, const float* __restrict__ Wout,
    const float* __restrict__ bout, float* __restrict__ feats) {
    __shared__ float smem[24832];                // 99328 B, carved per role
    const int tid = threadIdx.x;

    if (blockIdx.x >= 1088) {
        // ================= feat role: 256 blocks x 32 positions =================
        const int blk = blockIdx.x - 1088;
        f4_t* hbuf = (f4_t*)smem;                // [32][129] f4 (pad kills bank conflicts)
#pragma unroll
        for (int i = 0; i < 8; ++i) {
            int idx = i * 512 + tid;             // 0..4095 = [pos 0..31][j 0..127]
            int pl = idx >> 7, j = idx & 127;
            int p = blk * 32 + pl;
            int b = p >> 8, t = p & 255;
            int len = lens[b];
            int g = b >> 3;
            int Tg = lens[g * 8];                // group Tmax (lens sorted desc)
            const float* addr;
            if (j < 64) {                        // fwd h at t
                addr = hex + ((size_t)g * T_ + t) * 2048 + (b & 7) * 256 + j * 4;
            } else {                             // bwd h at un-reversed index
                int tr = t < len ? len - 1 - t : t;
                addr = hex + ((size_t)(4 + g) * T_ + tr) * 2048 + (b & 7) * 256 + (j - 64) * 4;
            }
            const bool need = (t < Tg);          // real data coming: retry until non-magic
            float a0, a1, a2, a3;
            int it = 0;
            for (;;) {
                a0 = __hip_atomic_load(addr + 0, __ATOMIC_RELAXED, __HIP_MEMORY_SCOPE_AGENT);
                a1 = __hip_atomic_load(addr + 1, __ATOMIC_RELAXED, __HIP_MEMORY_SCOPE_AGENT);
                a2 = __hip_atomic_load(addr + 2, __ATOMIC_RELAXED, __HIP_MEMORY_SCOPE_AGENT);
                a3 = __hip_atomic_load(addr + 3, __ATOMIC_RELAXED, __HIP_MEMORY_SCOPE_AGENT);
                if (!need) break;
                if (!(__float_as_uint(a0) == MAGICU || __float_as_uint(a1) == MAGICU ||
                      __float_as_uint(a2) == MAGICU || __float_as_uint(a3) == MAGICU)) break;
                if (++it > (1 << 22)) break;     // bail -> visible failure, not hang
                __builtin_amdgcn_s_sleep(16);    // long backoff: don't hammer the LLC
            }
            f4_t v; v.x = a0; v.y = a1; v.z = a2; v.w = a3;
            hbuf[pl * 129 + j] = v;
        }
        __syncthreads();
        if (tid < 384) {
            int pl = tid / 12, k = tid - pl * 12;
            int p = blk * 32 + pl;
            const float4* w0 = (const float4*)(Wout + (size_t)k * 512);
            const f4_t* hrow = hbuf + pl * 129;
            float acc = bout[k];
#pragma unroll 4
            for (int j = 0; j < 128; ++j) {
                f4_t h4 = hrow[j];
                float4 v4 = w0[j];
                acc += h4.x * v4.x + h4.y * v4.y + h4.z * v4.z + h4.w * v4.w;
            }
            feats[(size_t)p * K_ + k] = acc;
        }
        return;
    }

    if (blockIdx.x >= 64) {
        // ================= in_gemm role (512 threads, 128x128 tile) =================
        const int bi = blockIdx.x - 64;
        const int by = bi >> 4, sub = bi & 15;   // by-major order -> early t-tiles first
        const int dir = sub >> 3, bx = sub & 7;
        const int n0 = bx * 128, m0 = by * 128;
        float* As = smem;                        // [8][128]
        float* Bs = smem + 1024;                 // [8][128]
        const int rs = (tid & 255) >> 1, kc = (tid & 1) * 4;
        const float* srow;
        if (tid < 256) {
            int tok = tokA[dir * 8192 + m0 + rs];
            srow = emb + (size_t)tok * E_;
        } else {
            int np = n0 + rs;
            int wrow = ((np & 3) << 8) | (np >> 2);   // permuted col n'=u*4+g -> Wih row g*256+u
            srow = (dir ? Wih_b : Wih_f) + (size_t)wrow * E_;
        }
        float* Ls = (tid < 256) ? As : Bs;
        const int ty = tid >> 4, tx = tid & 15;  // ty 0..31 (4 rows), tx 0..15 (8 cols)

        float acc[4][8];
#pragma unroll
        for (int i = 0; i < 4; ++i)
#pragma unroll
            for (int j = 0; j < 8; ++j) acc[i][j] = 0.f;

        for (int k0 = 0; k0 < E_; k0 += 8) {
            float4 v = *(const float4*)(srow + k0 + kc);
            __syncthreads();
            Ls[(kc + 0) * 128 + rs] = v.x;
            Ls[(kc + 1) * 128 + rs] = v.y;
            Ls[(kc + 2) * 128 + rs] = v.z;
            Ls[(kc + 3) * 128 + rs] = v.w;
            __syncthreads();
#pragma unroll
            for (int k = 0; k < 8; ++k) {
                float4 a  = *(const float4*)&As[k * 128 + ty * 4];
                float4 b0 = *(const float4*)&Bs[k * 128 + tx * 8];
                float4 b1 = *(const float4*)&Bs[k * 128 + tx * 8 + 4];
                float af[4] = {a.x, a.y, a.z, a.w};
                float bf[8] = {b0.x, b0.y, b0.z, b0.w, b1.x, b1.y, b1.z, b1.w};
#pragma unroll
                for (int i = 0; i < 4; ++i)
#pragma unroll
                    for (int j = 0; j < 8; ++j) acc[i][j] += af[i] * bf[j];
            }
        }
        const float* bihp = dir ? bih_b : bih_f;
        const float* bhhp = dir ? bhh_b : bhh_f;
        float bias[8];
#pragma unroll
        for (int j = 0; j < 8; ++j) {
            int nn = n0 + tx * 8 + j;
            int wr = ((nn & 3) << 8) | (nn >> 2);
            bias[j] = bihp[wr] + bhhp[wr];
        }
#pragma unroll
        for (int i = 0; i < 4; ++i) {
            int m = m0 + ty * 4 + i;
            float* gp = G + ((size_t)dir * 8192 + m) * NG_ + n0 + tx * 8;
            f4_t o0, o1;
            o0.x = acc[i][0] + bias[0]; o0.y = acc[i][1] + bias[1];
            o0.z = acc[i][2] + bias[2]; o0.w = acc[i][3] + bias[3];
            o1.x = acc[i][4] + bias[4]; o1.y = acc[i][5] + bias[5];
            o1.z = acc[i][6] + bias[6]; o1.w = acc[i][7] + bias[7];
            asm volatile("global_store_dwordx4 %0, %1, off sc0 sc1" :: "v"(gp), "v"(o0) : "memory");
            asm volatile("global_store_dwordx4 %0, %1, off sc0 sc1" :: "v"(gp + 4), "v"(o1) : "memory");
        }
        asm volatile("s_waitcnt vmcnt(0)" ::: "memory");
        __syncthreads();
        if (tid == 0)
            __hip_atomic_fetch_add(gcnt + dir * 64 + by, 1,
                                   __ATOMIC_RELEASE, __HIP_MEMORY_SCOPE_AGENT);
        return;
    }

    // ================= lstm role: v11 + 64-lane act reduction =================
    float4* red4 = (float4*)smem;                // 512*11 f4 (90112 B)
    float4* hsA4 = (float4*)(smem + 22528);      // 256 f4: h[k][b0..3]
    float4* hsB4 = (float4*)(smem + 23552);      // 256 f4: h[k][b4..7]
    float4* hT4  = (float4*)(smem + 24576);      // 64 f4: own h [b][32u]

    const int wg = blockIdx.x;                   // dir*32 + bt*8 + ut
    const int dir = wg >> 5, bt = (wg >> 3) & 3, ut = wg & 7;
    const int wv = tid >> 6, ln = tid & 63;
    const int upair = ln & 15;
    const int kssub = ln >> 4;
    const int ksup = wv >> 1, bh = wv & 1;
    const int ks = ksup * 4 + kssub;
    const int sb = bh * 4 + (ln & 3);
    const int sk = ksup * 64 + (ln >> 2) * 4;
    const int speer = sk >> 5;

    const int Tmax = lens[bt * 8];               // lens sorted desc -> group max

    // ---- W into registers: 32 f4/thread ----
    const float4* WT4 = (const float4*)(WhhT + (size_t)dir * 256 * NG_);
    const int gu_e = ut * 32 + upair * 2;
    float4 We[16], Wo[16];
#pragma unroll
    for (int j = 0; j < 16; ++j) {
        We[j] = WT4[(ks * 16 + j) * 256 + gu_e];
        Wo[j] = WT4[(ks * 16 + j) * 256 + gu_e + 1];
    }

    // ---- wait for G tile by=0 (t=0..3) before the initial gp load ----
    {
        int it = 0;
        while (__hip_atomic_load(gcnt + dir * 64, __ATOMIC_RELAXED, __HIP_MEMORY_SCOPE_AGENT) < 8) {
            __builtin_amdgcn_s_sleep(8);
            if (++it > (1 << 22)) break;         // bail -> visible failure, not hang
        }
    }

    const bool is_act = (ln < 32);               // act lane: batch=wv, unit=ln
    float c = 0.f;
    float4 gpend = make_float4(0.f, 0.f, 0.f, 0.f);
    const float* Gd = G + (size_t)dir * 8192 * NG_;
    int gok = 1, gready = 0;                     // gp validity + highest known-ready by
    if (is_act) {
        c = c0[(dir * B_ + bt * 8 + wv) * HD_ + ut * 32 + ln];
        gpend = ((const float4*)(Gd + (size_t)(bt * 8 + wv) * NG_))[ut * 32 + ln];
    }

    float* hexg = hex + (size_t)(dir * 4 + bt) * T_ * 2048;  // [t][b*256+u]
    float4* hsX4 = bh ? hsB4 : hsA4;
    float* hsX = (float*)hsX4;

    f4_t pend;                                   // pre-issued poll data

    for (int t = 0; t < Tmax; ++t) {
        // ---- stage h(t-1) slice (wave-private region of hsX) ----
        float4 hv;
        if (t == 0) {
            hv = *(const float4*)(h0 + (size_t)(dir * B_ + bt * 8 + sb) * HD_ + sk);
        } else if (speer == ut) {
            hv = hT4[sb * 8 + ((sk & 31) >> 2)];         // own slice from LDS
        } else {
            asm volatile("s_waitcnt vmcnt(0)" ::: "memory");
            hv.x = pend.x; hv.y = pend.y; hv.z = pend.z; hv.w = pend.w;
            if (__float_as_uint(hv.x) == MAGICU || __float_as_uint(hv.y) == MAGICU ||
                __float_as_uint(hv.z) == MAGICU || __float_as_uint(hv.w) == MAGICU) {
                // loads-FIRST retry: the pend miss is ~300cy stale; data is often
                // already at the LLC. Sleep only after a confirmed fresh miss.
                const float* src = hexg + (size_t)(t - 1) * 2048 + sb * 256 + sk;
                int it = 0;
                for (;;) {
                    float a0 = __hip_atomic_load(src + 0, __ATOMIC_RELAXED, __HIP_MEMORY_SCOPE_AGENT);
                    float a1 = __hip_atomic_load(src + 1, __ATOMIC_RELAXED, __HIP_MEMORY_SCOPE_AGENT);
                    float a2 = __hip_atomic_load(src + 2, __ATOMIC_RELAXED, __HIP_MEMORY_SCOPE_AGENT);
                    float a3 = __hip_atomic_load(src + 3, __ATOMIC_RELAXED, __HIP_MEMORY_SCOPE_AGENT);
                    if (!(__float_as_uint(a0) == MAGICU || __float_as_uint(a1) == MAGICU ||
                          __float_as_uint(a2) == MAGICU || __float_as_uint(a3) == MAGICU)) {
                        hv = make_float4(a0, a1, a2, a3); break;
                    }
                    if (++it > (1 << 22)) break;   // bail -> visible failure, not hang
                    __builtin_amdgcn_s_sleep(1);
                }
            }
        }
        // transpose into [k][4b-half] (wave-private rows)
        hsX[(sk + 0) * 4 + (ln & 3)] = hv.x;
        hsX[(sk + 1) * 4 + (ln & 3)] = hv.y;
        hsX[(sk + 2) * 4 + (ln & 3)] = hv.z;
        hsX[(sk + 3) * 4 + (ln & 3)] = hv.w;
        asm volatile("s_waitcnt lgkmcnt(0)" ::: "memory");   // wave-local visibility

        // ---- FMA: 2 units x 4 gates x 4 batches x 16 k, W in regs ----
        float4 ae0 = {0,0,0,0}, ae1 = {0,0,0,0}, ae2 = {0,0,0,0}, ae3 = {0,0,0,0};
        float4 ao0 = {0,0,0,0}, ao1 = {0,0,0,0}, ao2 = {0,0,0,0}, ao3 = {0,0,0,0};
#pragma unroll
        for (int j = 0; j < 16; ++j) {
            float4 h4 = hsX4[ks * 16 + j];        // h[k][4b of this half]
            float4 we = We[j], wo = Wo[j];
            ae0.x += we.x*h4.x; ae0.y += we.y*h4.x; ae0.z += we.z*h4.x; ae0.w += we.w*h4.x;
            ae1.x += we.x*h4.y; ae1.y += we.y*h4.y; ae1.z += we.z*h4.y; ae1.w += we.w*h4.y;
            ae2.x += we.x*h4.z; ae2.y += we.y*h4.z; ae2.z += we.z*h4.z; ae2.w += we.w*h4.z;
            ae3.x += we.x*h4.w; ae3.y += we.y*h4.w; ae3.z += we.z*h4.w; ae3.w += we.w*h4.w;
            ao0.x += wo.x*h4.x; ao0.y += wo.y*h4.x; ao0.z += wo.z*h4.x; ao0.w += wo.w*h4.x;
            ao1.x += wo.x*h4.y; ao1.y += wo.y*h4.y; ao1.z += wo.z*h4.y; ao1.w += wo.w*h4.y;
            ao2.x += wo.x*h4.z; ao2.y += wo.y*h4.z; ao2.z += wo.z*h4.z; ao2.w += wo.w*h4.z;
            ao3.x += wo.x*h4.w; ao3.y += wo.y*h4.w; ao3.z += wo.z*h4.w; ao3.w += wo.w*h4.w;
        }
        // ---- write partials: row = (wv*4+kssub)*16 + upair, slot = par*4 + b ----
        {
            float4* r = &red4[((wv * 4 + kssub) * 16 + upair) * 11 + kssub];
            r[0] = ae0; r[1] = ae1; r[2] = ae2; r[3] = ae3;
            r[4] = ao0; r[5] = ao1; r[6] = ao2; r[7] = ao3;
        }
        asm volatile("s_waitcnt lgkmcnt(0)\n\ts_barrier" ::: "memory");   // barrier 1

        // ---- act reduction: ALL 64 lanes. Lane ln handles (b=wv, u=ln&31);
        // half = ln>>5 sums kq in {2h, 2h+1} (8 of 16 partials); shfl_xor(32)
        // combines the halves into the act lanes (ln<32).
        {
            const int b = wv, u = ln & 31, half = ln >> 5;
            const int bhv = b >> 2, bq = b & 3, up = u >> 1, par = u & 1;
            float rx = 0.f, ry = 0.f, rz = 0.f, rw = 0.f;
#pragma unroll
            for (int kq2 = 0; kq2 < 2; ++kq2) {
                const int kq = half * 2 + kq2;
#pragma unroll
                for (int kr = 0; kr < 4; ++kr) {
                    float4 p = red4[(((kq * 2 + bhv) * 4 + kr) * 16 + up) * 11 + kr + par * 4 + bq];
                    rx += p.x; ry += p.y; rz += p.z; rw += p.w;
                }
            }
            float ox = __shfl_xor(rx, 32);
            float oy = __shfl_xor(ry, 32);
            float oz = __shfl_xor(rz, 32);
            float ow = __shfl_xor(rw, 32);
            if (is_act) {
                if (!gok) {                       // gp for this step not validated: poll + LLC reload
                    const int byc = t >> 2;
                    int itc = 0;
                    while (__hip_atomic_load(gcnt + dir * 64 + byc, __ATOMIC_RELAXED,
                                             __HIP_MEMORY_SCOPE_AGENT) < 8) {
                        __builtin_amdgcn_s_sleep(2);
                        if (++itc > (1 << 22)) break;
                    }
                    const float* gsrc = Gd + ((size_t)t * B_ + bt * 8 + b) * NG_ + (size_t)(ut * 32 + u) * 4;
                    f4_t tmp;
                    asm volatile("global_load_dwordx4 %0, %1, off sc0 sc1\n\ts_waitcnt vmcnt(0)"
                                 : "=v"(tmp) : "v"(gsrc) : "memory");
                    gpend = make_float4(tmp.x, tmp.y, tmp.z, tmp.w);
                }
                float si = gpend.x + rx + ox;
                float sf = gpend.y + ry + oy;
                float sg = gpend.z + rz + oz;
                float so = gpend.w + rw + ow;
                c = sigf(sf) * c + sigf(si) * tanhf(sg);
                float h = sigf(so) * tanhf(c);
                ((float*)hT4)[b * 32 + u] = h;
                // publish: one contiguous 128B segment per wave, agent-coherent
                float* dst = hexg + (size_t)t * 2048 + b * 256 + ut * 32 + u;
                asm volatile("global_store_dword %0, %1, off sc0 sc1" :: "v"(dst), "v"(h) : "memory");
                if (t + 1 < Tmax) {               // gated prefetch for t+1
                    const int byn = (t + 1) >> 2;
                    if (byn > gready) {
                        int la = byn + 7; if (la > 63) la = 63;
                        if (__hip_atomic_load(gcnt + dir * 64 + la, __ATOMIC_RELAXED,
                                              __HIP_MEMORY_SCOPE_AGENT) >= 8) gready = la;
                        else if (__hip_atomic_load(gcnt + dir * 64 + byn, __ATOMIC_RELAXED,
                                                   __HIP_MEMORY_SCOPE_AGENT) >= 8) gready = byn;
                    }
                    if (byn <= gready) {
                        gpend = ((const float4*)(Gd + ((size_t)(t + 1) * B_ + bt * 8 + b) * NG_))[ut * 32 + u];
                        gok = 1;
                    } else gok = 0;               // skip -> no stale pull; reload next step
                }
            }
        }
        // ---- pre-issue next step's poll (flight overlaps barrier + peer publish) ----
        if (t + 1 < Tmax && speer != ut) {
            const float* nsrc = hexg + (size_t)t * 2048 + sb * 256 + sk;
            asm volatile("global_load_dwordx4 %0, %1, off sc0 sc1"
                         : "=v"(pend) : "v"(nsrc) : "memory");
        }
        asm volatile("s_waitcnt lgkmcnt(0)\n\ts_barrier" ::: "memory");   // barrier 2
    }
}

// ---------- Viterbi + backtrace: single block, feats prefetch, bp nibble-packed ----------
__global__ __launch_bounds__(512) void viterbi_k(
    const float* __restrict__ feats, const float* __restrict__ trans,
    const int* __restrict__ lens, float* __restrict__ out) {
    __shared__ float fv[2][B_][16];
    __shared__ float tl[K_][16];
    __shared__ unsigned char bp[T_][B_][6];    // 4-bit backpointers, 48KB
    __shared__ int best_last[B_];
    int tid = threadIdx.x;
    int b = tid >> 4, lane = tid & 15;
    if (tid < K_ * K_) tl[tid / 12][tid % 12] = trans[tid];
    if (lane < K_) fv[0][b][lane] = (lane == START_) ? 0.f : NEG_;
    __syncthreads();
    int len = lens[b];
    int pp = 0;
    float f_cur = 0.f;
    if (lane < K_) f_cur = feats[(size_t)b * T_ * K_ + lane];
    for (int t = 0; t < T_; ++t) {
        float f_nxt = 0.f;                       // prefetch t+1 before the compute chain
        if (t + 1 < T_ && lane < K_) f_nxt = feats[((size_t)b * T_ + t + 1) * K_ + lane];
        if (lane < K_) {
            float best = fv[pp][b][0] + tl[lane][0];
            int argp = 0;
#pragma unroll
            for (int p = 1; p < K_; ++p) {
                float v = fv[pp][b][p] + tl[lane][p];
                if (v > best) { best = v; argp = p; }   // strict > = first-max (matches jnp.argmax)
            }
            float nb = best + f_cur;
            fv[pp ^ 1][b][lane] = (t < len) ? nb : fv[pp][b][lane];
            int other = __shfl_xor(argp, 1);
            if ((lane & 1) == 0) bp[t][b][lane >> 1] = (unsigned char)(argp | (other << 4));
        }
        __syncthreads();
        pp ^= 1;
        f_cur = f_nxt;
    }
    if (lane == 0) {
        float best = fv[pp][b][0] + tl[STOP_][0];
        int bl = 0;
#pragma unroll
        for (int p = 1; p < K_; ++p) {
            float v = fv[pp][b][p] + tl[STOP_][p];
            if (v > best) { best = v; bl = p; }
        }
        out[b] = best;
        best_last[b] = bl;
    }
    __syncthreads();
    if (lane == 0) {
        int tag = best_last[b];
        for (int t = T_ - 1; t >= 0; --t) {
            int m = (t < len);
            out[B_ + b * T_ + t] = (float)(m ? tag : -1);
            if (m) tag = (bp[t][b][tag >> 1] >> ((tag & 1) * 4)) & 15;
        }
    }
}

extern "C" void kernel_launch(void* const* d_in, const int* in_sizes, int n_in,
                              void* d_out, int out_size, void* d_ws, size_t ws_size,
                              hipStream_t stream) {
    const int*   sent  = (const int*)d_in[0];
    const int*   lens  = (const int*)d_in[1];
    const float* emb   = (const float*)d_in[2];
    const float* Wih_f = (const float*)d_in[3];
    const float* Whh_f = (const float*)d_in[4];
    const float* bih_f = (const float*)d_in[5];
    const float* bhh_f = (const float*)d_in[6];
    const float* Wih_b = (const float*)d_in[7];
    const float* Whh_b = (const float*)d_in[8];
    const float* bih_b = (const float*)d_in[9];
    const float* bhh_b = (const float*)d_in[10];
    const float* h0    = (const float*)d_in[11];
    const float* c0    = (const float*)d_in[12];
    const float* Wout  = (const float*)d_in[13];
    const float* bout  = (const float*)d_in[14];
    const float* trans = (const float*)d_in[15];
    float* out = (float*)d_out;

    char* ws = (char*)d_ws;
    int*   tokA  = (int*)ws;                                  // 64 KB
    float* WhhT  = (float*)(ws + 65536);                      // 2 MB
    float* G     = (float*)(ws + 2162688);                    // 67.1 MB
    float* feats = (float*)(ws + 69271552);                   // 0.39 MB
    float* hex   = (float*)(ws + 69664768);                   // 16 MB  [8 groups][T][2048]
    // gcnt: 128 ints in d_out's preds region (out[32..159]); zeroed by prep,
    // fully overwritten by viterbi_k at the end. feats region is written
    // concurrently by the feat role, so an overlay there would race.
    int*   gcnt  = (int*)(out + 32);

    prep<<<4672, 256, 0, stream>>>(sent, lens, tokA, Whh_f, Whh_b, WhhT, hex, gcnt);
    mega<<<1344, 512, 0, stream>>>(emb, tokA, Wih_f, Wih_b, bih_f, bhh_f, bih_b, bhh_b,
                                   WhhT, G, h0, c0, lens, hex, gcnt, Wout, bout, feats);
    viterbi_k<<<1, 512, 0, stream>>>(feats, trans, lens, out);
}

// Round 13
// 1056.953 us; speedup vs baseline: 1.1285x; 1.0016x over previous
//
#include <hip/hip_runtime.h>
#include <math.h>

#define T_ 256
#define B_ 32
#define E_ 256
#define HD_ 256
#define NG_ 1024
#define K_ 12
#define START_ 10
#define STOP_ 11
#define NEG_ -10000.0f
#define MAGICU 0x40000000u   // 2.0f — |h|<1 so h can never be this bit pattern

typedef float f4_t __attribute__((ext_vector_type(4)));
typedef float f2_t __attribute__((ext_vector_type(2)));

__device__ __forceinline__ float sigf(float x) { return 1.0f / (1.0f + expf(-x)); }

// ---------- fused prep: hex sentinel fill + Whh^T + token gather + gcnt zero ----------
__global__ void prep(const int* __restrict__ sent, const int* __restrict__ lens,
                     int* __restrict__ tokA, const float* __restrict__ Wf,
                     const float* __restrict__ Wb, float* __restrict__ WT,
                     float* __restrict__ hex, int* __restrict__ gcnt) {
    const int b = blockIdx.x, tid = threadIdx.x;
    if (b < 4096) {
        // hex sentinel fill — only rows t < Tmax(group) are ever retry-polled:
        // lstm touches rows [0,Tmax); feat retries only for t < Tg. Rows >= Tmax
        // feed positions masked downstream (t >= Tg >= len) -> skip their fill.
        int i = b * 256 + tid;                   // f4 index into hex (1M total)
        int t = (i & 131071) >> 9;               // row within group (512 f4/row)
        int bt = (i >> 17) & 3;                  // bt within dir
        if (t < lens[bt * 8]) {
            float4 m = make_float4(2.0f, 2.0f, 2.0f, 2.0f);
            ((float4*)hex)[i] = m;
        }
        if (b == 0 && tid < 128) gcnt[tid] = 0;  // gcnt lives in d_out preds region
    } else if (b < 4608) {
        // Whh^T into [dir][k][u*4+gate] (unit-major gate packing)
        int b2 = b - 4096;
        int dir = b2 >> 8, k = b2 & 255, u = tid;
        const float* W = dir ? Wb : Wf;
        float4 v;
        v.x = W[(0 * HD_ + u) * HD_ + k];   // i
        v.y = W[(1 * HD_ + u) * HD_ + k];   // f
        v.z = W[(2 * HD_ + u) * HD_ + k];   // g
        v.w = W[(3 * HD_ + u) * HD_ + k];   // o
        ((float4*)(WT + ((size_t)dir * 256 + k) * NG_))[u] = v;
    } else {
        // token gather (bwd dir reversed within each sequence length)
        int e = (b - 4608) * 256 + tid;      // 0..16383 = [dir][t*32+b]
        int dir = e >> 13, m = e & 8191, t = m >> 5, bb = m & 31;
        int len = lens[bb];
        int tt = dir ? (t < len ? len - 1 - t : t) : t;
        tokA[e] = sent[bb * T_ + tt];
    }
}

// ---------- mega-kernel, 3 roles by blockIdx (r12 structure; one delta:
// the lstm FMA inner loop now uses v_pk_fma_f32 via __builtin_elementwise_fma
// on <2 x float> — 256 packed FMA/thread/step instead of 512 scalar, halving
// the FMA-issue floor on the serial critical path. Per-component ops and
// order are bit-identical; red4 layout unchanged; zero sync changes.):
//   [0,64)      v11 lstm + 64-lane act reduction + packed FMA
//   [64,1088)   in_gemm producers: sc0 sc1 write-through G stores + vmcnt(0)
//               drain + barrier + atomicAdd release (r6-proven)
//   [1088,1344) feat blocks: loads-first RELAXED agent polls, sleep(16) backoff
// All spins carry bail counters -> no hang possible.
__global__ __launch_bounds__(512, 1) void mega(
    const float* __restrict__ emb, const int* __restrict__ tokA,
    const float* __restrict__ Wih_f, const float* __restrict__ Wih_b,
    const float* __restrict__ bih_f, const float* __restrict__ bhh_f,
    const float* __restrict__ bih_b, const float* __restrict__ bhh_b,
    const float* __restrict__ WhhT, float* __restrict__ G,
    const float* __restrict__ h0, const float* __restrict__ c0,
    const int* __restrict__ lens, float* __restrict__ hex,
    int* __restrict__ gcnt, const float* __restrict__ Wout,
    const float* __restrict__ bout, float* __restrict__ feats) {
    __shared__ float smem[24832];                // 99328 B, carved per role
    const int tid = threadIdx.x;

    if (blockIdx.x >= 1088) {
        // ================= feat role: 256 blocks x 32 positions =================
        const int blk = blockIdx.x - 1088;
        f4_t* hbuf = (f4_t*)smem;                // [32][129] f4 (pad kills bank conflicts)
#pragma unroll
        for (int i = 0; i < 8; ++i) {
            int idx = i * 512 + tid;             // 0..4095 = [pos 0..31][j 0..127]
            int pl = idx >> 7, j = idx & 127;
            int p = blk * 32 + pl;
            int b = p >> 8, t = p & 255;
            int len = lens[b];
            int g = b >> 3;
            int Tg = lens[g * 8];                // group Tmax (lens sorted desc)
            const float* addr;
            if (j < 64) {                        // fwd h at t
                addr = hex + ((size_t)g * T_ + t) * 2048 + (b & 7) * 256 + j * 4;
            } else {                             // bwd h at un-reversed index
                int tr = t < len ? len - 1 - t : t;
                addr = hex + ((size_t)(4 + g) * T_ + tr) * 2048 + (b & 7) * 256 + (j - 64) * 4;
            }
            const bool need = (t < Tg);          // real data coming: retry until non-magic
            float a0, a1, a2, a3;
            int it = 0;
            for (;;) {
                a0 = __hip_atomic_load(addr + 0, __ATOMIC_RELAXED, __HIP_MEMORY_SCOPE_AGENT);
                a1 = __hip_atomic_load(addr + 1, __ATOMIC_RELAXED, __HIP_MEMORY_SCOPE_AGENT);
                a2 = __hip_atomic_load(addr + 2, __ATOMIC_RELAXED, __HIP_MEMORY_SCOPE_AGENT);
                a3 = __hip_atomic_load(addr + 3, __ATOMIC_RELAXED, __HIP_MEMORY_SCOPE_AGENT);
                if (!need) break;
                if (!(__float_as_uint(a0) == MAGICU || __float_as_uint(a1) == MAGICU ||
                      __float_as_uint(a2) == MAGICU || __float_as_uint(a3) == MAGICU)) break;
                if (++it > (1 << 22)) break;     // bail -> visible failure, not hang
                __builtin_amdgcn_s_sleep(16);    // long backoff: don't hammer the LLC
            }
            f4_t v; v.x = a0; v.y = a1; v.z = a2; v.w = a3;
            hbuf[pl * 129 + j] = v;
        }
        __syncthreads();
        if (tid < 384) {
            int pl = tid / 12, k = tid - pl * 12;
            int p = blk * 32 + pl;
            const float4* w0 = (const float4*)(Wout + (size_t)k * 512);
            const f4_t* hrow = hbuf + pl * 129;
            float acc = bout[k];
#pragma unroll 4
            for (int j = 0; j < 128; ++j) {
                f4_t h4 = hrow[j];
                float4 v4 = w0[j];
                acc += h4.x * v4.x + h4.y * v4.y + h4.z * v4.z + h4.w * v4.w;
            }
            feats[(size_t)p * K_ + k] = acc;
        }
        return;
    }

    if (blockIdx.x >= 64) {
        // ================= in_gemm role (512 threads, 128x128 tile) =================
        const int bi = blockIdx.x - 64;
        const int by = bi >> 4, sub = bi & 15;   // by-major order -> early t-tiles first
        const int dir = sub >> 3, bx = sub & 7;
        const int n0 = bx * 128, m0 = by * 128;
        float* As = smem;                        // [8][128]
        float* Bs = smem + 1024;                 // [8][128]
        const int rs = (tid & 255) >> 1, kc = (tid & 1) * 4;
        const float* srow;
        if (tid < 256) {
            int tok = tokA[dir * 8192 + m0 + rs];
            srow = emb + (size_t)tok * E_;
        } else {
            int np = n0 + rs;
            int wrow = ((np & 3) << 8) | (np >> 2);   // permuted col n'=u*4+g -> Wih row g*256+u
            srow = (dir ? Wih_b : Wih_f) + (size_t)wrow * E_;
        }
        float* Ls = (tid < 256) ? As : Bs;
        const int ty = tid >> 4, tx = tid & 15;  // ty 0..31 (4 rows), tx 0..15 (8 cols)

        float acc[4][8];
#pragma unroll
        for (int i = 0; i < 4; ++i)
#pragma unroll
            for (int j = 0; j < 8; ++j) acc[i][j] = 0.f;

        for (int k0 = 0; k0 < E_; k0 += 8) {
            float4 v = *(const float4*)(srow + k0 + kc);
            __syncthreads();
            Ls[(kc + 0) * 128 + rs] = v.x;
            Ls[(kc + 1) * 128 + rs] = v.y;
            Ls[(kc + 2) * 128 + rs] = v.z;
            Ls[(kc + 3) * 128 + rs] = v.w;
            __syncthreads();
#pragma unroll
            for (int k = 0; k < 8; ++k) {
                float4 a  = *(const float4*)&As[k * 128 + ty * 4];
                float4 b0 = *(const float4*)&Bs[k * 128 + tx * 8];
                float4 b1 = *(const float4*)&Bs[k * 128 + tx * 8 + 4];
                float af[4] = {a.x, a.y, a.z, a.w};
                float bf[8] = {b0.x, b0.y, b0.z, b0.w, b1.x, b1.y, b1.z, b1.w};
#pragma unroll
                for (int i = 0; i < 4; ++i)
#pragma unroll
                    for (int j = 0; j < 8; ++j) acc[i][j] += af[i] * bf[j];
            }
        }
        const float* bihp = dir ? bih_b : bih_f;
        const float* bhhp = dir ? bhh_b : bhh_f;
        float bias[8];
#pragma unroll
        for (int j = 0; j < 8; ++j) {
            int nn = n0 + tx * 8 + j;
            int wr = ((nn & 3) << 8) | (nn >> 2);
            bias[j] = bihp[wr] + bhhp[wr];
        }
#pragma unroll
        for (int i = 0; i < 4; ++i) {
            int m = m0 + ty * 4 + i;
            float* gp = G + ((size_t)dir * 8192 + m) * NG_ + n0 + tx * 8;
            f4_t o0, o1;
            o0.x = acc[i][0] + bias[0]; o0.y = acc[i][1] + bias[1];
            o0.z = acc[i][2] + bias[2]; o0.w = acc[i][3] + bias[3];
            o1.x = acc[i][4] + bias[4]; o1.y = acc[i][5] + bias[5];
            o1.z = acc[i][6] + bias[6]; o1.w = acc[i][7] + bias[7];
            asm volatile("global_store_dwordx4 %0, %1, off sc0 sc1" :: "v"(gp), "v"(o0) : "memory");
            asm volatile("global_store_dwordx4 %0, %1, off sc0 sc1" :: "v"(gp + 4), "v"(o1) : "memory");
        }
        asm volatile("s_waitcnt vmcnt(0)" ::: "memory");
        __syncthreads();
        if (tid == 0)
            __hip_atomic_fetch_add(gcnt + dir * 64 + by, 1,
                                   __ATOMIC_RELEASE, __HIP_MEMORY_SCOPE_AGENT);
        return;
    }

    // ================= lstm role: v11 + 64-lane act reduction + packed FMA =================
    float4* red4 = (float4*)smem;                // 512*11 f4 (90112 B)
    float4* hsA4 = (float4*)(smem + 22528);      // 256 f4: h[k][b0..3]
    float4* hsB4 = (float4*)(smem + 23552);      // 256 f4: h[k][b4..7]
    float4* hT4  = (float4*)(smem + 24576);      // 64 f4: own h [b][32u]

    const int wg = blockIdx.x;                   // dir*32 + bt*8 + ut
    const int dir = wg >> 5, bt = (wg >> 3) & 3, ut = wg & 7;
    const int wv = tid >> 6, ln = tid & 63;
    const int upair = ln & 15;
    const int kssub = ln >> 4;
    const int ksup = wv >> 1, bh = wv & 1;
    const int ks = ksup * 4 + kssub;
    const int sb = bh * 4 + (ln & 3);
    const int sk = ksup * 64 + (ln >> 2) * 4;
    const int speer = sk >> 5;

    const int Tmax = lens[bt * 8];               // lens sorted desc -> group max

    // ---- W into registers: 32 f4/thread (ext-vector for .lo/.hi pairs) ----
    const f4_t* WT4 = (const f4_t*)(WhhT + (size_t)dir * 256 * NG_);
    const int gu_e = ut * 32 + upair * 2;
    f4_t We[16], Wo[16];
#pragma unroll
    for (int j = 0; j < 16; ++j) {
        We[j] = WT4[(ks * 16 + j) * 256 + gu_e];
        Wo[j] = WT4[(ks * 16 + j) * 256 + gu_e + 1];
    }

    // ---- wait for G tile by=0 (t=0..3) before the initial gp load ----
    {
        int it = 0;
        while (__hip_atomic_load(gcnt + dir * 64, __ATOMIC_RELAXED, __HIP_MEMORY_SCOPE_AGENT) < 8) {
            __builtin_amdgcn_s_sleep(8);
            if (++it > (1 << 22)) break;         // bail -> visible failure, not hang
        }
    }

    const bool is_act = (ln < 32);               // act lane: batch=wv, unit=ln
    float c = 0.f;
    float4 gpend = make_float4(0.f, 0.f, 0.f, 0.f);
    const float* Gd = G + (size_t)dir * 8192 * NG_;
    int gok = 1, gready = 0;                     // gp validity + highest known-ready by
    if (is_act) {
        c = c0[(dir * B_ + bt * 8 + wv) * HD_ + ut * 32 + ln];
        gpend = ((const float4*)(Gd + (size_t)(bt * 8 + wv) * NG_))[ut * 32 + ln];
    }

    float* hexg = hex + (size_t)(dir * 4 + bt) * T_ * 2048;  // [t][b*256+u]
    float4* hsX4 = bh ? hsB4 : hsA4;
    float* hsX = (float*)hsX4;

    f4_t pend;                                   // pre-issued poll data

    for (int t = 0; t < Tmax; ++t) {
        // ---- stage h(t-1) slice (wave-private region of hsX) ----
        float4 hv;
        if (t == 0) {
            hv = *(const float4*)(h0 + (size_t)(dir * B_ + bt * 8 + sb) * HD_ + sk);
        } else if (speer == ut) {
            hv = hT4[sb * 8 + ((sk & 31) >> 2)];         // own slice from LDS
        } else {
            asm volatile("s_waitcnt vmcnt(0)" ::: "memory");
            hv.x = pend.x; hv.y = pend.y; hv.z = pend.z; hv.w = pend.w;
            if (__float_as_uint(hv.x) == MAGICU || __float_as_uint(hv.y) == MAGICU ||
                __float_as_uint(hv.z) == MAGICU || __float_as_uint(hv.w) == MAGICU) {
                // loads-FIRST retry: the pend miss is ~300cy stale; data is often
                // already at the LLC. Sleep only after a confirmed fresh miss.
                const float* src = hexg + (size_t)(t - 1) * 2048 + sb * 256 + sk;
                int it = 0;
                for (;;) {
                    float a0 = __hip_atomic_load(src + 0, __ATOMIC_RELAXED, __HIP_MEMORY_SCOPE_AGENT);
                    float a1 = __hip_atomic_load(src + 1, __ATOMIC_RELAXED, __HIP_MEMORY_SCOPE_AGENT);
                    float a2 = __hip_atomic_load(src + 2, __ATOMIC_RELAXED, __HIP_MEMORY_SCOPE_AGENT);
                    float a3 = __hip_atomic_load(src + 3, __ATOMIC_RELAXED, __HIP_MEMORY_SCOPE_AGENT);
                    if (!(__float_as_uint(a0) == MAGICU || __float_as_uint(a1) == MAGICU ||
                          __float_as_uint(a2) == MAGICU || __float_as_uint(a3) == MAGICU)) {
                        hv = make_float4(a0, a1, a2, a3); break;
                    }
                    if (++it > (1 << 22)) break;   // bail -> visible failure, not hang
                    __builtin_amdgcn_s_sleep(1);
                }
            }
        }
        // transpose into [k][4b-half] (wave-private rows)
        hsX[(sk + 0) * 4 + (ln & 3)] = hv.x;
        hsX[(sk + 1) * 4 + (ln & 3)] = hv.y;
        hsX[(sk + 2) * 4 + (ln & 3)] = hv.z;
        hsX[(sk + 3) * 4 + (ln & 3)] = hv.w;
        asm volatile("s_waitcnt lgkmcnt(0)" ::: "memory");   // wave-local visibility

        // ---- FMA: 2 units x 4 gates x 4 batches x 16 k, packed fp32 pairs ----
        // acc pairs: aXl=(old aX.x, aX.y), aXh=(old aX.z, aX.w). Per j: 16
        // v_pk_fma_f32 instead of 32 v_fma_f32. Same per-component math/order.
        f2_t ae0l={0,0}, ae0h={0,0}, ae1l={0,0}, ae1h={0,0};
        f2_t ae2l={0,0}, ae2h={0,0}, ae3l={0,0}, ae3h={0,0};
        f2_t ao0l={0,0}, ao0h={0,0}, ao1l={0,0}, ao1h={0,0};
        f2_t ao2l={0,0}, ao2h={0,0}, ao3l={0,0}, ao3h={0,0};
#pragma unroll
        for (int j = 0; j < 16; ++j) {
            float4 h4 = hsX4[ks * 16 + j];        // h[k][4b of this half]
            f2_t hx = {h4.x, h4.x}, hy = {h4.y, h4.y};
            f2_t hz = {h4.z, h4.z}, hw = {h4.w, h4.w};
            f2_t wel = We[j].lo, weh = We[j].hi;
            f2_t wol = Wo[j].lo, woh = Wo[j].hi;
            ae0l = __builtin_elementwise_fma(wel, hx, ae0l);
            ae0h = __builtin_elementwise_fma(weh, hx, ae0h);
            ae1l = __builtin_elementwise_fma(wel, hy, ae1l);
            ae1h = __builtin_elementwise_fma(weh, hy, ae1h);
            ae2l = __builtin_elementwise_fma(wel, hz, ae2l);
            ae2h = __builtin_elementwise_fma(weh, hz, ae2h);
            ae3l = __builtin_elementwise_fma(wel, hw, ae3l);
            ae3h = __builtin_elementwise_fma(weh, hw, ae3h);
            ao0l = __builtin_elementwise_fma(wol, hx, ao0l);
            ao0h = __builtin_elementwise_fma(woh, hx, ao0h);
            ao1l = __builtin_elementwise_fma(wol, hy, ao1l);
            ao1h = __builtin_elementwise_fma(woh, hy, ao1h);
            ao2l = __builtin_elementwise_fma(wol, hz, ao2l);
            ao2h = __builtin_elementwise_fma(woh, hz, ao2h);
            ao3l = __builtin_elementwise_fma(wol, hw, ao3l);
            ao3h = __builtin_elementwise_fma(woh, hw, ao3h);
        }
        // ---- write partials (layout identical to r12) ----
        {
            float4* r = &red4[((wv * 4 + kssub) * 16 + upair) * 11 + kssub];
            r[0] = make_float4(ae0l.x, ae0l.y, ae0h.x, ae0h.y);
            r[1] = make_float4(ae1l.x, ae1l.y, ae1h.x, ae1h.y);
            r[2] = make_float4(ae2l.x, ae2l.y, ae2h.x, ae2h.y);
            r[3] = make_float4(ae3l.x, ae3l.y, ae3h.x, ae3h.y);
            r[4] = make_float4(ao0l.x, ao0l.y, ao0h.x, ao0h.y);
            r[5] = make_float4(ao1l.x, ao1l.y, ao1h.x, ao1h.y);
            r[6] = make_float4(ao2l.x, ao2l.y, ao2h.x, ao2h.y);
            r[7] = make_float4(ao3l.x, ao3l.y, ao3h.x, ao3h.y);
        }
        asm volatile("s_waitcnt lgkmcnt(0)\n\ts_barrier" ::: "memory");   // barrier 1

        // ---- act reduction: ALL 64 lanes. Lane ln handles (b=wv, u=ln&31);
        // half = ln>>5 sums kq in {2h, 2h+1} (8 of 16 partials); shfl_xor(32)
        // combines the halves into the act lanes (ln<32).
        {
            const int b = wv, u = ln & 31, half = ln >> 5;
            const int bhv = b >> 2, bq = b & 3, up = u >> 1, par = u & 1;
            float rx = 0.f, ry = 0.f, rz = 0.f, rw = 0.f;
#pragma unroll
            for (int kq2 = 0; kq2 < 2; ++kq2) {
                const int kq = half * 2 + kq2;
#pragma unroll
                for (int kr = 0; kr < 4; ++kr) {
                    float4 p = red4[(((kq * 2 + bhv) * 4 + kr) * 16 + up) * 11 + kr + par * 4 + bq];
                    rx += p.x; ry += p.y; rz += p.z; rw += p.w;
                }
            }
            float ox = __shfl_xor(rx, 32);
            float oy = __shfl_xor(ry, 32);
            float oz = __shfl_xor(rz, 32);
            float ow = __shfl_xor(rw, 32);
            if (is_act) {
                if (!gok) {                       // gp for this step not validated: poll + LLC reload
                    const int byc = t >> 2;
                    int itc = 0;
                    while (__hip_atomic_load(gcnt + dir * 64 + byc, __ATOMIC_RELAXED,
                                             __HIP_MEMORY_SCOPE_AGENT) < 8) {
                        __builtin_amdgcn_s_sleep(2);
                        if (++itc > (1 << 22)) break;
                    }
                    const float* gsrc = Gd + ((size_t)t * B_ + bt * 8 + b) * NG_ + (size_t)(ut * 32 + u) * 4;
                    f4_t tmp;
                    asm volatile("global_load_dwordx4 %0, %1, off sc0 sc1\n\ts_waitcnt vmcnt(0)"
                                 : "=v"(tmp) : "v"(gsrc) : "memory");
                    gpend = make_float4(tmp.x, tmp.y, tmp.z, tmp.w);
                }
                float si = gpend.x + rx + ox;
                float sf = gpend.y + ry + oy;
                float sg = gpend.z + rz + oz;
                float so = gpend.w + rw + ow;
                c = sigf(sf) * c + sigf(si) * tanhf(sg);
                float h = sigf(so) * tanhf(c);
                ((float*)hT4)[b * 32 + u] = h;
                // publish: one contiguous 128B segment per wave, agent-coherent
                float* dst = hexg + (size_t)t * 2048 + b * 256 + ut * 32 + u;
                asm volatile("global_store_dword %0, %1, off sc0 sc1" :: "v"(dst), "v"(h) : "memory");
                if (t + 1 < Tmax) {               // gated prefetch for t+1
                    const int byn = (t + 1) >> 2;
                    if (byn > gready) {
                        int la = byn + 7; if (la > 63) la = 63;
                        if (__hip_atomic_load(gcnt + dir * 64 + la, __ATOMIC_RELAXED,
                                              __HIP_MEMORY_SCOPE_AGENT) >= 8) gready = la;
                        else if (__hip_atomic_load(gcnt + dir * 64 + byn, __ATOMIC_RELAXED,
                                                   __HIP_MEMORY_SCOPE_AGENT) >= 8) gready = byn;
                    }
                    if (byn <= gready) {
                        gpend = ((const float4*)(Gd + ((size_t)(t + 1) * B_ + bt * 8 + b) * NG_))[ut * 32 + u];
                        gok = 1;
                    } else gok = 0;               // skip -> no stale pull; reload next step
                }
            }
        }
        // ---- pre-issue next step's poll (flight overlaps barrier + peer publish) ----
        if (t + 1 < Tmax && speer != ut) {
            const float* nsrc = hexg + (size_t)t * 2048 + sb * 256 + sk;
            asm volatile("global_load_dwordx4 %0, %1, off sc0 sc1"
                         : "=v"(pend) : "v"(nsrc) : "memory");
        }
        asm volatile("s_waitcnt lgkmcnt(0)\n\ts_barrier" ::: "memory");   // barrier 2
    }
}

// ---------- Viterbi + backtrace: single block, feats prefetch, bp nibble-packed ----------
__global__ __launch_bounds__(512) void viterbi_k(
    const float* __restrict__ feats, const float* __restrict__ trans,
    const int* __restrict__ lens, float* __restrict__ out) {
    __shared__ float fv[2][B_][16];
    __shared__ float tl[K_][16];
    __shared__ unsigned char bp[T_][B_][6];    // 4-bit backpointers, 48KB
    __shared__ int best_last[B_];
    int tid = threadIdx.x;
    int b = tid >> 4, lane = tid & 15;
    if (tid < K_ * K_) tl[tid / 12][tid % 12] = trans[tid];
    if (lane < K_) fv[0][b][lane] = (lane == START_) ? 0.f : NEG_;
    __syncthreads();
    int len = lens[b];
    int pp = 0;
    float f_cur = 0.f;
    if (lane < K_) f_cur = feats[(size_t)b * T_ * K_ + lane];
    for (int t = 0; t < T_; ++t) {
        float f_nxt = 0.f;                       // prefetch t+1 before the compute chain
        if (t + 1 < T_ && lane < K_) f_nxt = feats[((size_t)b * T_ + t + 1) * K_ + lane];
        if (lane < K_) {
            float best = fv[pp][b][0] + tl[lane][0];
            int argp = 0;
#pragma unroll
            for (int p = 1; p < K_; ++p) {
                float v = fv[pp][b][p] + tl[lane][p];
                if (v > best) { best = v; argp = p; }   // strict > = first-max (matches jnp.argmax)
            }
            float nb = best + f_cur;
            fv[pp ^ 1][b][lane] = (t < len) ? nb : fv[pp][b][lane];
            int other = __shfl_xor(argp, 1);
            if ((lane & 1) == 0) bp[t][b][lane >> 1] = (unsigned char)(argp | (other << 4));
        }
        __syncthreads();
        pp ^= 1;
        f_cur = f_nxt;
    }
    if (lane == 0) {
        float best = fv[pp][b][0] + tl[STOP_][0];
        int bl = 0;
#pragma unroll
        for (int p = 1; p < K_; ++p) {
            float v = fv[pp][b][p] + tl[STOP_][p];
            if (v > best) { best = v; bl = p; }
        }
        out[b] = best;
        best_last[b] = bl;
    }
    __syncthreads();
    if (lane == 0) {
        int tag = best_last[b];
        for (int t = T_ - 1; t >= 0; --t) {
            int m = (t < len);
            out[B_ + b * T_ + t] = (float)(m ? tag : -1);
            if (m) tag = (bp[t][b][tag >> 1] >> ((tag & 1) * 4)) & 15;
        }
    }
}

extern "C" void kernel_launch(void* const* d_in, const int* in_sizes, int n_in,
                              void* d_out, int out_size, void* d_ws, size_t ws_size,
                              hipStream_t stream) {
    const int*   sent  = (const int*)d_in[0];
    const int*   lens  = (const int*)d_in[1];
    const float* emb   = (const float*)d_in[2];
    const float* Wih_f = (const float*)d_in[3];
    const float* Whh_f = (const float*)d_in[4];
    const float* bih_f = (const float*)d_in[5];
    const float* bhh_f = (const float*)d_in[6];
    const float* Wih_b = (const float*)d_in[7];
    const float* Whh_b = (const float*)d_in[8];
    const float* bih_b = (const float*)d_in[9];
    const float* bhh_b = (const float*)d_in[10];
    const float* h0    = (const float*)d_in[11];
    const float* c0    = (const float*)d_in[12];
    const float* Wout  = (const float*)d_in[13];
    const float* bout  = (const float*)d_in[14];
    const float* trans = (const float*)d_in[15];
    float* out = (float*)d_out;

    char* ws = (char*)d_ws;
    int*   tokA  = (int*)ws;                                  // 64 KB
    float* WhhT  = (float*)(ws + 65536);                      // 2 MB
    float* G     = (float*)(ws + 2162688);                    // 67.1 MB
    float* feats = (float*)(ws + 69271552);                   // 0.39 MB
    float* hex   = (float*)(ws + 69664768);                   // 16 MB  [8 groups][T][2048]
    // gcnt: 128 ints in d_out's preds region (out[32..159]); zeroed by prep,
    // fully overwritten by viterbi_k at the end. feats region is written
    // concurrently by the feat role, so an overlay there would race.
    int*   gcnt  = (int*)(out + 32);

    prep<<<4672, 256, 0, stream>>>(sent, lens, tokA, Whh_f, Whh_b, WhhT, hex, gcnt);
    mega<<<1344, 512, 0, stream>>>(emb, tokA, Wih_f, Wih_b, bih_f, bhh_f, bih_b, bhh_b,
                                   WhhT, G, h0, c0, lens, hex, gcnt, Wout, bout, feats);
    viterbi_k<<<1, 512, 0, stream>>>(feats, trans, lens, out);
}

// Round 14
// 1015.812 us; speedup vs baseline: 1.1742x; 1.0405x over previous
//
#include <hip/hip_runtime.h>
#include <math.h>

#define T_ 256
#define B_ 32
#define E_ 256
#define HD_ 256
#define NG_ 1024
#define K_ 12
#define START_ 10
#define STOP_ 11
#define NEG_ -10000.0f
#define MAGICU 0x40000000u   // 2.0f — |h|<1 so h can never be this bit pattern

typedef float f4_t __attribute__((ext_vector_type(4)));
typedef float f2_t __attribute__((ext_vector_type(2)));

__device__ __forceinline__ float sigf(float x) { return 1.0f / (1.0f + expf(-x)); }
// fast act-path forms: native v_exp_f32/v_rcp_f32, saturation-safe at +-inf
// (x->-inf: exp2(+inf)=inf -> rcp=0; x->+inf: exp2(-inf)=0 -> 1). ~1-2 ulp.
__device__ __forceinline__ float sigfast(float x) {
    return __builtin_amdgcn_rcpf(1.0f + __builtin_amdgcn_exp2f(x * -1.4426950408889634f));
}
__device__ __forceinline__ float tanhfast(float x) {
    return 1.0f - 2.0f * __builtin_amdgcn_rcpf(__builtin_amdgcn_exp2f(x * 2.8853900817779268f) + 1.0f);
}

// ---------- fused prep: hex sentinel fill + Whh^T + token gather + gcnt zero ----------
__global__ void prep(const int* __restrict__ sent, const int* __restrict__ lens,
                     int* __restrict__ tokA, const float* __restrict__ Wf,
                     const float* __restrict__ Wb, float* __restrict__ WT,
                     float* __restrict__ hex, int* __restrict__ gcnt) {
    const int b = blockIdx.x, tid = threadIdx.x;
    if (b < 4096) {
        // hex sentinel fill — only rows t < Tmax(group) are ever retry-polled:
        // lstm touches rows [0,Tmax); feat retries only for t < Tg. Rows >= Tmax
        // feed positions masked downstream (t >= Tg >= len) -> skip their fill.
        int i = b * 256 + tid;                   // f4 index into hex (1M total)
        int t = (i & 131071) >> 9;               // row within group (512 f4/row)
        int bt = (i >> 17) & 3;                  // bt within dir
        if (t < lens[bt * 8]) {
            float4 m = make_float4(2.0f, 2.0f, 2.0f, 2.0f);
            ((float4*)hex)[i] = m;
        }
        if (b == 0 && tid < 128) gcnt[tid] = 0;  // gcnt lives in d_out preds region
    } else if (b < 4608) {
        // Whh^T into [dir][k][u*4+gate] (unit-major gate packing)
        int b2 = b - 4096;
        int dir = b2 >> 8, k = b2 & 255, u = tid;
        const float* W = dir ? Wb : Wf;
        float4 v;
        v.x = W[(0 * HD_ + u) * HD_ + k];   // i
        v.y = W[(1 * HD_ + u) * HD_ + k];   // f
        v.z = W[(2 * HD_ + u) * HD_ + k];   // g
        v.w = W[(3 * HD_ + u) * HD_ + k];   // o
        ((float4*)(WT + ((size_t)dir * 256 + k) * NG_))[u] = v;
    } else {
        // token gather (bwd dir reversed within each sequence length)
        int e = (b - 4608) * 256 + tid;      // 0..16383 = [dir][t*32+b]
        int dir = e >> 13, m = e & 8191, t = m >> 5, bb = m & 31;
        int len = lens[bb];
        int tt = dir ? (t < len ? len - 1 - t : t) : t;
        tokA[e] = sent[bb * T_ + tt];
    }
}

// ---------- mega-kernel, 3 roles by blockIdx (r13 structure; one delta:
// act-path transcendentals use native v_exp_f32/v_rcp_f32 forms — publish
// lands ~200-300cy earlier each step, raising peers' pend-poll hit rate):
//   [0,64)      v11 lstm + 64-lane act reduction + packed FMA + fast act
//   [64,1088)   in_gemm producers: sc0 sc1 write-through G stores + vmcnt(0)
//               drain + barrier + atomicAdd release (r6-proven)
//   [1088,1344) feat blocks: loads-first RELAXED agent polls, sleep(16) backoff
// All spins carry bail counters -> no hang possible.
__global__ __launch_bounds__(512, 1) void mega(
    const float* __restrict__ emb, const int* __restrict__ tokA,
    const float* __restrict__ Wih_f, const float* __restrict__ Wih_b,
    const float* __restrict__ bih_f, const float* __restrict__ bhh_f,
    const float* __restrict__ bih_b, const float* __restrict__ bhh_b,
    const float* __restrict__ WhhT, float* __restrict__ G,
    const float* __restrict__ h0, const float* __restrict__ c0,
    const int* __restrict__ lens, float* __restrict__ hex,
    int* __restrict__ gcnt, const float* __restrict__ Wout,
    const float* __restrict__ bout, float* __restrict__ feats) {
    __shared__ float smem[24832];                // 99328 B, carved per role
    const int tid = threadIdx.x;

    if (blockIdx.x >= 1088) {
        // ================= feat role: 256 blocks x 32 positions =================
        const int blk = blockIdx.x - 1088;
        f4_t* hbuf = (f4_t*)smem;                // [32][129] f4 (pad kills bank conflicts)
#pragma unroll
        for (int i = 0; i < 8; ++i) {
            int idx = i * 512 + tid;             // 0..4095 = [pos 0..31][j 0..127]
            int pl = idx >> 7, j = idx & 127;
            int p = blk * 32 + pl;
            int b = p >> 8, t = p & 255;
            int len = lens[b];
            int g = b >> 3;
            int Tg = lens[g * 8];                // group Tmax (lens sorted desc)
            const float* addr;
            if (j < 64) {                        // fwd h at t
                addr = hex + ((size_t)g * T_ + t) * 2048 + (b & 7) * 256 + j * 4;
            } else {                             // bwd h at un-reversed index
                int tr = t < len ? len - 1 - t : t;
                addr = hex + ((size_t)(4 + g) * T_ + tr) * 2048 + (b & 7) * 256 + (j - 64) * 4;
            }
            const bool need = (t < Tg);          // real data coming: retry until non-magic
            float a0, a1, a2, a3;
            int it = 0;
            for (;;) {
                a0 = __hip_atomic_load(addr + 0, __ATOMIC_RELAXED, __HIP_MEMORY_SCOPE_AGENT);
                a1 = __hip_atomic_load(addr + 1, __ATOMIC_RELAXED, __HIP_MEMORY_SCOPE_AGENT);
                a2 = __hip_atomic_load(addr + 2, __ATOMIC_RELAXED, __HIP_MEMORY_SCOPE_AGENT);
                a3 = __hip_atomic_load(addr + 3, __ATOMIC_RELAXED, __HIP_MEMORY_SCOPE_AGENT);
                if (!need) break;
                if (!(__float_as_uint(a0) == MAGICU || __float_as_uint(a1) == MAGICU ||
                      __float_as_uint(a2) == MAGICU || __float_as_uint(a3) == MAGICU)) break;
                if (++it > (1 << 22)) break;     // bail -> visible failure, not hang
                __builtin_amdgcn_s_sleep(16);    // long backoff: don't hammer the LLC
            }
            f4_t v; v.x = a0; v.y = a1; v.z = a2; v.w = a3;
            hbuf[pl * 129 + j] = v;
        }
        __syncthreads();
        if (tid < 384) {
            int pl = tid / 12, k = tid - pl * 12;
            int p = blk * 32 + pl;
            const float4* w0 = (const float4*)(Wout + (size_t)k * 512);
            const f4_t* hrow = hbuf + pl * 129;
            float acc = bout[k];
#pragma unroll 4
            for (int j = 0; j < 128; ++j) {
                f4_t h4 = hrow[j];
                float4 v4 = w0[j];
                acc += h4.x * v4.x + h4.y * v4.y + h4.z * v4.z + h4.w * v4.w;
            }
            feats[(size_t)p * K_ + k] = acc;
        }
        return;
    }

    if (blockIdx.x >= 64) {
        // ================= in_gemm role (512 threads, 128x128 tile) =================
        const int bi = blockIdx.x - 64;
        const int by = bi >> 4, sub = bi & 15;   // by-major order -> early t-tiles first
        const int dir = sub >> 3, bx = sub & 7;
        const int n0 = bx * 128, m0 = by * 128;
        float* As = smem;                        // [8][128]
        float* Bs = smem + 1024;                 // [8][128]
        const int rs = (tid & 255) >> 1, kc = (tid & 1) * 4;
        const float* srow;
        if (tid < 256) {
            int tok = tokA[dir * 8192 + m0 + rs];
            srow = emb + (size_t)tok * E_;
        } else {
            int np = n0 + rs;
            int wrow = ((np & 3) << 8) | (np >> 2);   // permuted col n'=u*4+g -> Wih row g*256+u
            srow = (dir ? Wih_b : Wih_f) + (size_t)wrow * E_;
        }
        float* Ls = (tid < 256) ? As : Bs;
        const int ty = tid >> 4, tx = tid & 15;  // ty 0..31 (4 rows), tx 0..15 (8 cols)

        float acc[4][8];
#pragma unroll
        for (int i = 0; i < 4; ++i)
#pragma unroll
            for (int j = 0; j < 8; ++j) acc[i][j] = 0.f;

        for (int k0 = 0; k0 < E_; k0 += 8) {
            float4 v = *(const float4*)(srow + k0 + kc);
            __syncthreads();
            Ls[(kc + 0) * 128 + rs] = v.x;
            Ls[(kc + 1) * 128 + rs] = v.y;
            Ls[(kc + 2) * 128 + rs] = v.z;
            Ls[(kc + 3) * 128 + rs] = v.w;
            __syncthreads();
#pragma unroll
            for (int k = 0; k < 8; ++k) {
                float4 a  = *(const float4*)&As[k * 128 + ty * 4];
                float4 b0 = *(const float4*)&Bs[k * 128 + tx * 8];
                float4 b1 = *(const float4*)&Bs[k * 128 + tx * 8 + 4];
                float af[4] = {a.x, a.y, a.z, a.w};
                float bf[8] = {b0.x, b0.y, b0.z, b0.w, b1.x, b1.y, b1.z, b1.w};
#pragma unroll
                for (int i = 0; i < 4; ++i)
#pragma unroll
                    for (int j = 0; j < 8; ++j) acc[i][j] += af[i] * bf[j];
            }
        }
        const float* bihp = dir ? bih_b : bih_f;
        const float* bhhp = dir ? bhh_b : bhh_f;
        float bias[8];
#pragma unroll
        for (int j = 0; j < 8; ++j) {
            int nn = n0 + tx * 8 + j;
            int wr = ((nn & 3) << 8) | (nn >> 2);
            bias[j] = bihp[wr] + bhhp[wr];
        }
#pragma unroll
        for (int i = 0; i < 4; ++i) {
            int m = m0 + ty * 4 + i;
            float* gp = G + ((size_t)dir * 8192 + m) * NG_ + n0 + tx * 8;
            f4_t o0, o1;
            o0.x = acc[i][0] + bias[0]; o0.y = acc[i][1] + bias[1];
            o0.z = acc[i][2] + bias[2]; o0.w = acc[i][3] + bias[3];
            o1.x = acc[i][4] + bias[4]; o1.y = acc[i][5] + bias[5];
            o1.z = acc[i][6] + bias[6]; o1.w = acc[i][7] + bias[7];
            asm volatile("global_store_dwordx4 %0, %1, off sc0 sc1" :: "v"(gp), "v"(o0) : "memory");
            asm volatile("global_store_dwordx4 %0, %1, off sc0 sc1" :: "v"(gp + 4), "v"(o1) : "memory");
        }
        asm volatile("s_waitcnt vmcnt(0)" ::: "memory");
        __syncthreads();
        if (tid == 0)
            __hip_atomic_fetch_add(gcnt + dir * 64 + by, 1,
                                   __ATOMIC_RELEASE, __HIP_MEMORY_SCOPE_AGENT);
        return;
    }

    // ======== lstm role: v11 + 64-lane act reduction + packed FMA + fast act ========
    float4* red4 = (float4*)smem;                // 512*11 f4 (90112 B)
    float4* hsA4 = (float4*)(smem + 22528);      // 256 f4: h[k][b0..3]
    float4* hsB4 = (float4*)(smem + 23552);      // 256 f4: h[k][b4..7]
    float4* hT4  = (float4*)(smem + 24576);      // 64 f4: own h [b][32u]

    const int wg = blockIdx.x;                   // dir*32 + bt*8 + ut
    const int dir = wg >> 5, bt = (wg >> 3) & 3, ut = wg & 7;
    const int wv = tid >> 6, ln = tid & 63;
    const int upair = ln & 15;
    const int kssub = ln >> 4;
    const int ksup = wv >> 1, bh = wv & 1;
    const int ks = ksup * 4 + kssub;
    const int sb = bh * 4 + (ln & 3);
    const int sk = ksup * 64 + (ln >> 2) * 4;
    const int speer = sk >> 5;

    const int Tmax = lens[bt * 8];               // lens sorted desc -> group max

    // ---- W into registers: 32 f4/thread (ext-vector for .lo/.hi pairs) ----
    const f4_t* WT4 = (const f4_t*)(WhhT + (size_t)dir * 256 * NG_);
    const int gu_e = ut * 32 + upair * 2;
    f4_t We[16], Wo[16];
#pragma unroll
    for (int j = 0; j < 16; ++j) {
        We[j] = WT4[(ks * 16 + j) * 256 + gu_e];
        Wo[j] = WT4[(ks * 16 + j) * 256 + gu_e + 1];
    }

    // ---- wait for G tile by=0 (t=0..3) before the initial gp load ----
    {
        int it = 0;
        while (__hip_atomic_load(gcnt + dir * 64, __ATOMIC_RELAXED, __HIP_MEMORY_SCOPE_AGENT) < 8) {
            __builtin_amdgcn_s_sleep(8);
            if (++it > (1 << 22)) break;         // bail -> visible failure, not hang
        }
    }

    const bool is_act = (ln < 32);               // act lane: batch=wv, unit=ln
    float c = 0.f;
    float4 gpend = make_float4(0.f, 0.f, 0.f, 0.f);
    const float* Gd = G + (size_t)dir * 8192 * NG_;
    int gok = 1, gready = 0;                     // gp validity + highest known-ready by
    if (is_act) {
        c = c0[(dir * B_ + bt * 8 + wv) * HD_ + ut * 32 + ln];
        gpend = ((const float4*)(Gd + (size_t)(bt * 8 + wv) * NG_))[ut * 32 + ln];
    }

    float* hexg = hex + (size_t)(dir * 4 + bt) * T_ * 2048;  // [t][b*256+u]
    float4* hsX4 = bh ? hsB4 : hsA4;
    float* hsX = (float*)hsX4;

    f4_t pend;                                   // pre-issued poll data

    for (int t = 0; t < Tmax; ++t) {
        // ---- stage h(t-1) slice (wave-private region of hsX) ----
        float4 hv;
        if (t == 0) {
            hv = *(const float4*)(h0 + (size_t)(dir * B_ + bt * 8 + sb) * HD_ + sk);
        } else if (speer == ut) {
            hv = hT4[sb * 8 + ((sk & 31) >> 2)];         // own slice from LDS
        } else {
            asm volatile("s_waitcnt vmcnt(0)" ::: "memory");
            hv.x = pend.x; hv.y = pend.y; hv.z = pend.z; hv.w = pend.w;
            if (__float_as_uint(hv.x) == MAGICU || __float_as_uint(hv.y) == MAGICU ||
                __float_as_uint(hv.z) == MAGICU || __float_as_uint(hv.w) == MAGICU) {
                // loads-FIRST retry: the pend miss is ~300cy stale; data is often
                // already at the LLC. Sleep only after a confirmed fresh miss.
                const float* src = hexg + (size_t)(t - 1) * 2048 + sb * 256 + sk;
                int it = 0;
                for (;;) {
                    float a0 = __hip_atomic_load(src + 0, __ATOMIC_RELAXED, __HIP_MEMORY_SCOPE_AGENT);
                    float a1 = __hip_atomic_load(src + 1, __ATOMIC_RELAXED, __HIP_MEMORY_SCOPE_AGENT);
                    float a2 = __hip_atomic_load(src + 2, __ATOMIC_RELAXED, __HIP_MEMORY_SCOPE_AGENT);
                    float a3 = __hip_atomic_load(src + 3, __ATOMIC_RELAXED, __HIP_MEMORY_SCOPE_AGENT);
                    if (!(__float_as_uint(a0) == MAGICU || __float_as_uint(a1) == MAGICU ||
                          __float_as_uint(a2) == MAGICU || __float_as_uint(a3) == MAGICU)) {
                        hv = make_float4(a0, a1, a2, a3); break;
                    }
                    if (++it > (1 << 22)) break;   // bail -> visible failure, not hang
                    __builtin_amdgcn_s_sleep(1);
                }
            }
        }
        // transpose into [k][4b-half] (wave-private rows)
        hsX[(sk + 0) * 4 + (ln & 3)] = hv.x;
        hsX[(sk + 1) * 4 + (ln & 3)] = hv.y;
        hsX[(sk + 2) * 4 + (ln & 3)] = hv.z;
        hsX[(sk + 3) * 4 + (ln & 3)] = hv.w;
        asm volatile("s_waitcnt lgkmcnt(0)" ::: "memory");   // wave-local visibility

        // ---- FMA: 2 units x 4 gates x 4 batches x 16 k, packed fp32 pairs ----
        f2_t ae0l={0,0}, ae0h={0,0}, ae1l={0,0}, ae1h={0,0};
        f2_t ae2l={0,0}, ae2h={0,0}, ae3l={0,0}, ae3h={0,0};
        f2_t ao0l={0,0}, ao0h={0,0}, ao1l={0,0}, ao1h={0,0};
        f2_t ao2l={0,0}, ao2h={0,0}, ao3l={0,0}, ao3h={0,0};
#pragma unroll
        for (int j = 0; j < 16; ++j) {
            float4 h4 = hsX4[ks * 16 + j];        // h[k][4b of this half]
            f2_t hx = {h4.x, h4.x}, hy = {h4.y, h4.y};
            f2_t hz = {h4.z, h4.z}, hw = {h4.w, h4.w};
            f2_t wel = We[j].lo, weh = We[j].hi;
            f2_t wol = Wo[j].lo, woh = Wo[j].hi;
            ae0l = __builtin_elementwise_fma(wel, hx, ae0l);
            ae0h = __builtin_elementwise_fma(weh, hx, ae0h);
            ae1l = __builtin_elementwise_fma(wel, hy, ae1l);
            ae1h = __builtin_elementwise_fma(weh, hy, ae1h);
            ae2l = __builtin_elementwise_fma(wel, hz, ae2l);
            ae2h = __builtin_elementwise_fma(weh, hz, ae2h);
            ae3l = __builtin_elementwise_fma(wel, hw, ae3l);
            ae3h = __builtin_elementwise_fma(weh, hw, ae3h);
            ao0l = __builtin_elementwise_fma(wol, hx, ao0l);
            ao0h = __builtin_elementwise_fma(woh, hx, ao0h);
            ao1l = __builtin_elementwise_fma(wol, hy, ao1l);
            ao1h = __builtin_elementwise_fma(woh, hy, ao1h);
            ao2l = __builtin_elementwise_fma(wol, hz, ao2l);
            ao2h = __builtin_elementwise_fma(woh, hz, ao2h);
            ao3l = __builtin_elementwise_fma(wol, hw, ao3l);
            ao3h = __builtin_elementwise_fma(woh, hw, ao3h);
        }
        // ---- write partials (layout identical to r12) ----
        {
            float4* r = &red4[((wv * 4 + kssub) * 16 + upair) * 11 + kssub];
            r[0] = make_float4(ae0l.x, ae0l.y, ae0h.x, ae0h.y);
            r[1] = make_float4(ae1l.x, ae1l.y, ae1h.x, ae1h.y);
            r[2] = make_float4(ae2l.x, ae2l.y, ae2h.x, ae2h.y);
            r[3] = make_float4(ae3l.x, ae3l.y, ae3h.x, ae3h.y);
            r[4] = make_float4(ao0l.x, ao0l.y, ao0h.x, ao0h.y);
            r[5] = make_float4(ao1l.x, ao1l.y, ao1h.x, ao1h.y);
            r[6] = make_float4(ao2l.x, ao2l.y, ao2h.x, ao2h.y);
            r[7] = make_float4(ao3l.x, ao3l.y, ao3h.x, ao3h.y);
        }
        asm volatile("s_waitcnt lgkmcnt(0)\n\ts_barrier" ::: "memory");   // barrier 1

        // ---- act reduction: ALL 64 lanes; shfl_xor(32) combines halves ----
        {
            const int b = wv, u = ln & 31, half = ln >> 5;
            const int bhv = b >> 2, bq = b & 3, up = u >> 1, par = u & 1;
            float rx = 0.f, ry = 0.f, rz = 0.f, rw = 0.f;
#pragma unroll
            for (int kq2 = 0; kq2 < 2; ++kq2) {
                const int kq = half * 2 + kq2;
#pragma unroll
                for (int kr = 0; kr < 4; ++kr) {
                    float4 p = red4[(((kq * 2 + bhv) * 4 + kr) * 16 + up) * 11 + kr + par * 4 + bq];
                    rx += p.x; ry += p.y; rz += p.z; rw += p.w;
                }
            }
            float ox = __shfl_xor(rx, 32);
            float oy = __shfl_xor(ry, 32);
            float oz = __shfl_xor(rz, 32);
            float ow = __shfl_xor(rw, 32);
            if (is_act) {
                if (!gok) {                       // gp for this step not validated: poll + LLC reload
                    const int byc = t >> 2;
                    int itc = 0;
                    while (__hip_atomic_load(gcnt + dir * 64 + byc, __ATOMIC_RELAXED,
                                             __HIP_MEMORY_SCOPE_AGENT) < 8) {
                        __builtin_amdgcn_s_sleep(2);
                        if (++itc > (1 << 22)) break;
                    }
                    const float* gsrc = Gd + ((size_t)t * B_ + bt * 8 + b) * NG_ + (size_t)(ut * 32 + u) * 4;
                    f4_t tmp;
                    asm volatile("global_load_dwordx4 %0, %1, off sc0 sc1\n\ts_waitcnt vmcnt(0)"
                                 : "=v"(tmp) : "v"(gsrc) : "memory");
                    gpend = make_float4(tmp.x, tmp.y, tmp.z, tmp.w);
                }
                float si = gpend.x + rx + ox;
                float sf = gpend.y + ry + oy;
                float sg = gpend.z + rz + oz;
                float so = gpend.w + rw + ow;
                c = sigfast(sf) * c + sigfast(si) * tanhfast(sg);
                float h = sigfast(so) * tanhfast(c);
                ((float*)hT4)[b * 32 + u] = h;
                // publish: one contiguous 128B segment per wave, agent-coherent
                float* dst = hexg + (size_t)t * 2048 + b * 256 + ut * 32 + u;
                asm volatile("global_store_dword %0, %1, off sc0 sc1" :: "v"(dst), "v"(h) : "memory");
                if (t + 1 < Tmax) {               // gated prefetch for t+1
                    const int byn = (t + 1) >> 2;
                    if (byn > gready) {
                        int la = byn + 7; if (la > 63) la = 63;
                        if (__hip_atomic_load(gcnt + dir * 64 + la, __ATOMIC_RELAXED,
                                              __HIP_MEMORY_SCOPE_AGENT) >= 8) gready = la;
                        else if (__hip_atomic_load(gcnt + dir * 64 + byn, __ATOMIC_RELAXED,
                                                   __HIP_MEMORY_SCOPE_AGENT) >= 8) gready = byn;
                    }
                    if (byn <= gready) {
                        gpend = ((const float4*)(Gd + ((size_t)(t + 1) * B_ + bt * 8 + b) * NG_))[ut * 32 + u];
                        gok = 1;
                    } else gok = 0;               // skip -> no stale pull; reload next step
                }
            }
        }
        // ---- pre-issue next step's poll (flight overlaps barrier + peer publish) ----
        if (t + 1 < Tmax && speer != ut) {
            const float* nsrc = hexg + (size_t)t * 2048 + sb * 256 + sk;
            asm volatile("global_load_dwordx4 %0, %1, off sc0 sc1"
                         : "=v"(pend) : "v"(nsrc) : "memory");
        }
        asm volatile("s_waitcnt lgkmcnt(0)\n\ts_barrier" ::: "memory");   // barrier 2
    }
}

// ---------- Viterbi + backtrace: single block, feats prefetch, bp nibble-packed ----------
__global__ __launch_bounds__(512) void viterbi_k(
    const float* __restrict__ feats, const float* __restrict__ trans,
    const int* __restrict__ lens, float* __restrict__ out) {
    __shared__ float fv[2][B_][16];
    __shared__ float tl[K_][16];
    __shared__ unsigned char bp[T_][B_][6];    // 4-bit backpointers, 48KB
    __shared__ int best_last[B_];
    int tid = threadIdx.x;
    int b = tid >> 4, lane = tid & 15;
    if (tid < K_ * K_) tl[tid / 12][tid % 12] = trans[tid];
    if (lane < K_) fv[0][b][lane] = (lane == START_) ? 0.f : NEG_;
    __syncthreads();
    int len = lens[b];
    int pp = 0;
    float f_cur = 0.f;
    if (lane < K_) f_cur = feats[(size_t)b * T_ * K_ + lane];
    for (int t = 0; t < T_; ++t) {
        float f_nxt = 0.f;                       // prefetch t+1 before the compute chain
        if (t + 1 < T_ && lane < K_) f_nxt = feats[((size_t)b * T_ + t + 1) * K_ + lane];
        if (lane < K_) {
            float best = fv[pp][b][0] + tl[lane][0];
            int argp = 0;
#pragma unroll
            for (int p = 1; p < K_; ++p) {
                float v = fv[pp][b][p] + tl[lane][p];
                if (v > best) { best = v; argp = p; }   // strict > = first-max (matches jnp.argmax)
            }
            float nb = best + f_cur;
            fv[pp ^ 1][b][lane] = (t < len) ? nb : fv[pp][b][lane];
            int other = __shfl_xor(argp, 1);
            if ((lane & 1) == 0) bp[t][b][lane >> 1] = (unsigned char)(argp | (other << 4));
        }
        __syncthreads();
        pp ^= 1;
        f_cur = f_nxt;
    }
    if (lane == 0) {
        float best = fv[pp][b][0] + tl[STOP_][0];
        int bl = 0;
#pragma unroll
        for (int p = 1; p < K_; ++p) {
            float v = fv[pp][b][p] + tl[STOP_][p];
            if (v > best) { best = v; bl = p; }
        }
        out[b] = best;
        best_last[b] = bl;
    }
    __syncthreads();
    if (lane == 0) {
        int tag = best_last[b];
        for (int t = T_ - 1; t >= 0; --t) {
            int m = (t < len);
            out[B_ + b * T_ + t] = (float)(m ? tag : -1);
            if (m) tag = (bp[t][b][tag >> 1] >> ((tag & 1) * 4)) & 15;
        }
    }
}

extern "C" void kernel_launch(void* const* d_in, const int* in_sizes, int n_in,
                              void* d_out, int out_size, void* d_ws, size_t ws_size,
                              hipStream_t stream) {
    const int*   sent  = (const int*)d_in[0];
    const int*   lens  = (const int*)d_in[1];
    const float* emb   = (const float*)d_in[2];
    const float* Wih_f = (const float*)d_in[3];
    const float* Whh_f = (const float*)d_in[4];
    const float* bih_f = (const float*)d_in[5];
    const float* bhh_f = (const float*)d_in[6];
    const float* Wih_b = (const float*)d_in[7];
    const float* Whh_b = (const float*)d_in[8];
    const float* bih_b = (const float*)d_in[9];
    const float* bhh_b = (const float*)d_in[10];
    const float* h0    = (const float*)d_in[11];
    const float* c0    = (const float*)d_in[12];
    const float* Wout  = (const float*)d_in[13];
    const float* bout  = (const float*)d_in[14];
    const float* trans = (const float*)d_in[15];
    float* out = (float*)d_out;

    char* ws = (char*)d_ws;
    int*   tokA  = (int*)ws;                                  // 64 KB
    float* WhhT  = (float*)(ws + 65536);                      // 2 MB
    float* G     = (float*)(ws + 2162688);                    // 67.1 MB
    float* feats = (float*)(ws + 69271552);                   // 0.39 MB
    float* hex   = (float*)(ws + 69664768);                   // 16 MB  [8 groups][T][2048]
    // gcnt: 128 ints in d_out's preds region (out[32..159]); zeroed by prep,
    // fully overwritten by viterbi_k at the end. feats region is written
    // concurrently by the feat role, so an overlay there would race.
    int*   gcnt  = (int*)(out + 32);

    prep<<<4672, 256, 0, stream>>>(sent, lens, tokA, Whh_f, Whh_b, WhhT, hex, gcnt);
    mega<<<1344, 512, 0, stream>>>(emb, tokA, Wih_f, Wih_b, bih_f, bhh_f, bih_b, bhh_b,
                                   WhhT, G, h0, c0, lens, hex, gcnt, Wout, bout, feats);
    viterbi_k<<<1, 512, 0, stream>>>(feats, trans, lens, out);
}

// Round 15
// 995.055 us; speedup vs baseline: 1.1987x; 1.0209x over previous
//
#include <hip/hip_runtime.h>
#include <math.h>

#define T_ 256
#define B_ 32
#define E_ 256
#define HD_ 256
#define NG_ 1024
#define K_ 12
#define START_ 10
#define STOP_ 11
#define NEG_ -10000.0f
#define MAGICU 0x40000000u   // 2.0f — |h|<1 so h can never be this bit pattern

typedef float f4_t __attribute__((ext_vector_type(4)));
typedef float f2_t __attribute__((ext_vector_type(2)));

__device__ __forceinline__ float sigf(float x) { return 1.0f / (1.0f + expf(-x)); }
// fast act-path forms: native v_exp_f32/v_rcp_f32, saturation-safe at +-inf
__device__ __forceinline__ float sigfast(float x) {
    return __builtin_amdgcn_rcpf(1.0f + __builtin_amdgcn_exp2f(x * -1.4426950408889634f));
}
__device__ __forceinline__ float tanhfast(float x) {
    return 1.0f - 2.0f * __builtin_amdgcn_rcpf(__builtin_amdgcn_exp2f(x * 2.8853900817779268f) + 1.0f);
}

// ---------- fused prep: hex sentinel fill + Whh^T + token gather + gcnt zero ----------
__global__ void prep(const int* __restrict__ sent, const int* __restrict__ lens,
                     int* __restrict__ tokA, const float* __restrict__ Wf,
                     const float* __restrict__ Wb, float* __restrict__ WT,
                     float* __restrict__ hex, int* __restrict__ gcnt) {
    const int b = blockIdx.x, tid = threadIdx.x;
    if (b < 4096) {
        // hex sentinel fill — only rows t < Tmax(group) are ever retry-polled.
        int i = b * 256 + tid;                   // f4 index into hex (1M total)
        int t = (i & 131071) >> 9;               // row within group (512 f4/row)
        int bt = (i >> 17) & 3;                  // bt within dir
        if (t < lens[bt * 8]) {
            float4 m = make_float4(2.0f, 2.0f, 2.0f, 2.0f);
            ((float4*)hex)[i] = m;
        }
        if (b == 0 && tid < 128) gcnt[tid] = 0;  // gcnt lives in d_out preds region
    } else if (b < 4608) {
        // Whh^T into [dir][k][u*4+gate] (unit-major gate packing)
        int b2 = b - 4096;
        int dir = b2 >> 8, k = b2 & 255, u = tid;
        const float* W = dir ? Wb : Wf;
        float4 v;
        v.x = W[(0 * HD_ + u) * HD_ + k];   // i
        v.y = W[(1 * HD_ + u) * HD_ + k];   // f
        v.z = W[(2 * HD_ + u) * HD_ + k];   // g
        v.w = W[(3 * HD_ + u) * HD_ + k];   // o
        ((float4*)(WT + ((size_t)dir * 256 + k) * NG_))[u] = v;
    } else {
        // token gather (bwd dir reversed within each sequence length)
        int e = (b - 4608) * 256 + tid;      // 0..16383 = [dir][t*32+b]
        int dir = e >> 13, m = e & 8191, t = m >> 5, bb = m & 31;
        int len = lens[bb];
        int tt = dir ? (t < len ? len - 1 - t : t) : t;
        tokA[e] = sent[bb * T_ + tt];
    }
}

// ---------- mega-kernel, 3 roles by blockIdx (r14 structure; one delta:
// COUNTED consume waits. Per-step wave VMEM order is [publish store]->[pend
// poll]->[G prefetch (now asm)]. Stage waits vmcnt(1) when the wave issued G
// last step (completes store+pend, leaves G in flight under FMA+barrier),
// vmcnt(0) otherwise; act waits vmcnt(0) before reading gpend (~1300cy after
// issue -> free). gi = ballot(gissue) is wave-uniform. Every branch completes
// pend before its registers are read. Protocol semantics unchanged.):
//   [0,64)      lstm + 64-lane act red. + packed FMA + fast act + counted waits
//   [64,1088)   in_gemm producers (r6-proven publish discipline)
//   [1088,1344) feat blocks (loads-first RELAXED agent polls, sleep(16))
// All spins carry bail counters -> no hang possible.
__global__ __launch_bounds__(512, 1) void mega(
    const float* __restrict__ emb, const int* __restrict__ tokA,
    const float* __restrict__ Wih_f, const float* __restrict__ Wih_b,
    const float* __restrict__ bih_f, const float* __restrict__ bhh_f,
    const float* __restrict__ bih_b, const float* __restrict__ bhh_b,
    const float* __restrict__ WhhT, float* __restrict__ G,
    const float* __restrict__ h0, const float* __restrict__ c0,
    const int* __restrict__ lens, float* __restrict__ hex,
    int* __restrict__ gcnt, const float* __restrict__ Wout,
    const float* __restrict__ bout, float* __restrict__ feats) {
    __shared__ float smem[24832];                // 99328 B, carved per role
    const int tid = threadIdx.x;

    if (blockIdx.x >= 1088) {
        // ================= feat role: 256 blocks x 32 positions =================
        const int blk = blockIdx.x - 1088;
        f4_t* hbuf = (f4_t*)smem;                // [32][129] f4 (pad kills bank conflicts)
#pragma unroll
        for (int i = 0; i < 8; ++i) {
            int idx = i * 512 + tid;             // 0..4095 = [pos 0..31][j 0..127]
            int pl = idx >> 7, j = idx & 127;
            int p = blk * 32 + pl;
            int b = p >> 8, t = p & 255;
            int len = lens[b];
            int g = b >> 3;
            int Tg = lens[g * 8];                // group Tmax (lens sorted desc)
            const float* addr;
            if (j < 64) {                        // fwd h at t
                addr = hex + ((size_t)g * T_ + t) * 2048 + (b & 7) * 256 + j * 4;
            } else {                             // bwd h at un-reversed index
                int tr = t < len ? len - 1 - t : t;
                addr = hex + ((size_t)(4 + g) * T_ + tr) * 2048 + (b & 7) * 256 + (j - 64) * 4;
            }
            const bool need = (t < Tg);          // real data coming: retry until non-magic
            float a0, a1, a2, a3;
            int it = 0;
            for (;;) {
                a0 = __hip_atomic_load(addr + 0, __ATOMIC_RELAXED, __HIP_MEMORY_SCOPE_AGENT);
                a1 = __hip_atomic_load(addr + 1, __ATOMIC_RELAXED, __HIP_MEMORY_SCOPE_AGENT);
                a2 = __hip_atomic_load(addr + 2, __ATOMIC_RELAXED, __HIP_MEMORY_SCOPE_AGENT);
                a3 = __hip_atomic_load(addr + 3, __ATOMIC_RELAXED, __HIP_MEMORY_SCOPE_AGENT);
                if (!need) break;
                if (!(__float_as_uint(a0) == MAGICU || __float_as_uint(a1) == MAGICU ||
                      __float_as_uint(a2) == MAGICU || __float_as_uint(a3) == MAGICU)) break;
                if (++it > (1 << 22)) break;     // bail -> visible failure, not hang
                __builtin_amdgcn_s_sleep(16);    // long backoff: don't hammer the LLC
            }
            f4_t v; v.x = a0; v.y = a1; v.z = a2; v.w = a3;
            hbuf[pl * 129 + j] = v;
        }
        __syncthreads();
        if (tid < 384) {
            int pl = tid / 12, k = tid - pl * 12;
            int p = blk * 32 + pl;
            const float4* w0 = (const float4*)(Wout + (size_t)k * 512);
            const f4_t* hrow = hbuf + pl * 129;
            float acc = bout[k];
#pragma unroll 4
            for (int j = 0; j < 128; ++j) {
                f4_t h4 = hrow[j];
                float4 v4 = w0[j];
                acc += h4.x * v4.x + h4.y * v4.y + h4.z * v4.z + h4.w * v4.w;
            }
            feats[(size_t)p * K_ + k] = acc;
        }
        return;
    }

    if (blockIdx.x >= 64) {
        // ================= in_gemm role (512 threads, 128x128 tile) =================
        const int bi = blockIdx.x - 64;
        const int by = bi >> 4, sub = bi & 15;   // by-major order -> early t-tiles first
        const int dir = sub >> 3, bx = sub & 7;
        const int n0 = bx * 128, m0 = by * 128;
        float* As = smem;                        // [8][128]
        float* Bs = smem + 1024;                 // [8][128]
        const int rs = (tid & 255) >> 1, kc = (tid & 1) * 4;
        const float* srow;
        if (tid < 256) {
            int tok = tokA[dir * 8192 + m0 + rs];
            srow = emb + (size_t)tok * E_;
        } else {
            int np = n0 + rs;
            int wrow = ((np & 3) << 8) | (np >> 2);   // permuted col n'=u*4+g -> Wih row g*256+u
            srow = (dir ? Wih_b : Wih_f) + (size_t)wrow * E_;
        }
        float* Ls = (tid < 256) ? As : Bs;
        const int ty = tid >> 4, tx = tid & 15;  // ty 0..31 (4 rows), tx 0..15 (8 cols)

        float acc[4][8];
#pragma unroll
        for (int i = 0; i < 4; ++i)
#pragma unroll
            for (int j = 0; j < 8; ++j) acc[i][j] = 0.f;

        for (int k0 = 0; k0 < E_; k0 += 8) {
            float4 v = *(const float4*)(srow + k0 + kc);
            __syncthreads();
            Ls[(kc + 0) * 128 + rs] = v.x;
            Ls[(kc + 1) * 128 + rs] = v.y;
            Ls[(kc + 2) * 128 + rs] = v.z;
            Ls[(kc + 3) * 128 + rs] = v.w;
            __syncthreads();
#pragma unroll
            for (int k = 0; k < 8; ++k) {
                float4 a  = *(const float4*)&As[k * 128 + ty * 4];
                float4 b0 = *(const float4*)&Bs[k * 128 + tx * 8];
                float4 b1 = *(const float4*)&Bs[k * 128 + tx * 8 + 4];
                float af[4] = {a.x, a.y, a.z, a.w};
                float bf[8] = {b0.x, b0.y, b0.z, b0.w, b1.x, b1.y, b1.z, b1.w};
#pragma unroll
                for (int i = 0; i < 4; ++i)
#pragma unroll
                    for (int j = 0; j < 8; ++j) acc[i][j] += af[i] * bf[j];
            }
        }
        const float* bihp = dir ? bih_b : bih_f;
        const float* bhhp = dir ? bhh_b : bhh_f;
        float bias[8];
#pragma unroll
        for (int j = 0; j < 8; ++j) {
            int nn = n0 + tx * 8 + j;
            int wr = ((nn & 3) << 8) | (nn >> 2);
            bias[j] = bihp[wr] + bhhp[wr];
        }
#pragma unroll
        for (int i = 0; i < 4; ++i) {
            int m = m0 + ty * 4 + i;
            float* gp = G + ((size_t)dir * 8192 + m) * NG_ + n0 + tx * 8;
            f4_t o0, o1;
            o0.x = acc[i][0] + bias[0]; o0.y = acc[i][1] + bias[1];
            o0.z = acc[i][2] + bias[2]; o0.w = acc[i][3] + bias[3];
            o1.x = acc[i][4] + bias[4]; o1.y = acc[i][5] + bias[5];
            o1.z = acc[i][6] + bias[6]; o1.w = acc[i][7] + bias[7];
            asm volatile("global_store_dwordx4 %0, %1, off sc0 sc1" :: "v"(gp), "v"(o0) : "memory");
            asm volatile("global_store_dwordx4 %0, %1, off sc0 sc1" :: "v"(gp + 4), "v"(o1) : "memory");
        }
        asm volatile("s_waitcnt vmcnt(0)" ::: "memory");
        __syncthreads();
        if (tid == 0)
            __hip_atomic_fetch_add(gcnt + dir * 64 + by, 1,
                                   __ATOMIC_RELEASE, __HIP_MEMORY_SCOPE_AGENT);
        return;
    }

    // ==== lstm role: packed FMA + fast act + 64-lane reduction + counted waits ====
    float4* red4 = (float4*)smem;                // 512*11 f4 (90112 B)
    float4* hsA4 = (float4*)(smem + 22528);      // 256 f4: h[k][b0..3]
    float4* hsB4 = (float4*)(smem + 23552);      // 256 f4: h[k][b4..7]
    float4* hT4  = (float4*)(smem + 24576);      // 64 f4: own h [b][32u]

    const int wg = blockIdx.x;                   // dir*32 + bt*8 + ut
    const int dir = wg >> 5, bt = (wg >> 3) & 3, ut = wg & 7;
    const int wv = tid >> 6, ln = tid & 63;
    const int upair = ln & 15;
    const int kssub = ln >> 4;
    const int ksup = wv >> 1, bh = wv & 1;
    const int ks = ksup * 4 + kssub;
    const int sb = bh * 4 + (ln & 3);
    const int sk = ksup * 64 + (ln >> 2) * 4;
    const int speer = sk >> 5;

    const int Tmax = lens[bt * 8];               // lens sorted desc -> group max

    // ---- W into registers: 32 f4/thread (ext-vector for .lo/.hi pairs) ----
    const f4_t* WT4 = (const f4_t*)(WhhT + (size_t)dir * 256 * NG_);
    const int gu_e = ut * 32 + upair * 2;
    f4_t We[16], Wo[16];
#pragma unroll
    for (int j = 0; j < 16; ++j) {
        We[j] = WT4[(ks * 16 + j) * 256 + gu_e];
        Wo[j] = WT4[(ks * 16 + j) * 256 + gu_e + 1];
    }

    // ---- wait for G tile by=0 (t=0..3) before the initial gp load ----
    {
        int it = 0;
        while (__hip_atomic_load(gcnt + dir * 64, __ATOMIC_RELAXED, __HIP_MEMORY_SCOPE_AGENT) < 8) {
            __builtin_amdgcn_s_sleep(8);
            if (++it > (1 << 22)) break;         // bail -> visible failure, not hang
        }
    }

    const bool is_act = (ln < 32);               // act lane: batch=wv, unit=ln
    float c = 0.f;
    f4_t gpend = {0.f, 0.f, 0.f, 0.f};
    const float* Gd = G + (size_t)dir * 8192 * NG_;
    int gok = 1, gready = 0;                     // gp validity + highest known-ready by
    int gi = 0;                                  // wave-uniform: G issued last step
    if (is_act) {
        c = c0[(dir * B_ + bt * 8 + wv) * HD_ + ut * 32 + ln];
        gpend = ((const f4_t*)(Gd + (size_t)(bt * 8 + wv) * NG_))[ut * 32 + ln];
    }

    float* hexg = hex + (size_t)(dir * 4 + bt) * T_ * 2048;  // [t][b*256+u]
    float4* hsX4 = bh ? hsB4 : hsA4;
    float* hsX = (float*)hsX4;

    f4_t pend;                                   // pre-issued poll data

    for (int t = 0; t < Tmax; ++t) {
        // ---- stage h(t-1) slice (wave-private region of hsX) ----
        float4 hv;
        if (t == 0) {
            hv = *(const float4*)(h0 + (size_t)(dir * B_ + bt * 8 + sb) * HD_ + sk);
        } else if (speer == ut) {
            hv = hT4[sb * 8 + ((sk & 31) >> 2)];         // own slice from LDS
        } else {
            // counted wait: completes [store, pend]; leaves G (newest) in flight
            // when the wave issued it (gi). Every branch completes pend before use.
            if (gi) { asm volatile("s_waitcnt vmcnt(1)" : "+v"(pend) :: "memory"); }
            else    { asm volatile("s_waitcnt vmcnt(0)" : "+v"(pend) :: "memory"); }
            hv.x = pend.x; hv.y = pend.y; hv.z = pend.z; hv.w = pend.w;
            if (__float_as_uint(hv.x) == MAGICU || __float_as_uint(hv.y) == MAGICU ||
                __float_as_uint(hv.z) == MAGICU || __float_as_uint(hv.w) == MAGICU) {
                // loads-FIRST retry (pend miss info is stale); sleep after fresh miss.
                const float* src = hexg + (size_t)(t - 1) * 2048 + sb * 256 + sk;
                int it = 0;
                for (;;) {
                    float a0 = __hip_atomic_load(src + 0, __ATOMIC_RELAXED, __HIP_MEMORY_SCOPE_AGENT);
                    float a1 = __hip_atomic_load(src + 1, __ATOMIC_RELAXED, __HIP_MEMORY_SCOPE_AGENT);
                    float a2 = __hip_atomic_load(src + 2, __ATOMIC_RELAXED, __HIP_MEMORY_SCOPE_AGENT);
                    float a3 = __hip_atomic_load(src + 3, __ATOMIC_RELAXED, __HIP_MEMORY_SCOPE_AGENT);
                    if (!(__float_as_uint(a0) == MAGICU || __float_as_uint(a1) == MAGICU ||
                          __float_as_uint(a2) == MAGICU || __float_as_uint(a3) == MAGICU)) {
                        hv = make_float4(a0, a1, a2, a3); break;
                    }
                    if (++it > (1 << 22)) break;   // bail -> visible failure, not hang
                    __builtin_amdgcn_s_sleep(1);
                }
            }
        }
        // transpose into [k][4b-half] (wave-private rows)
        hsX[(sk + 0) * 4 + (ln & 3)] = hv.x;
        hsX[(sk + 1) * 4 + (ln & 3)] = hv.y;
        hsX[(sk + 2) * 4 + (ln & 3)] = hv.z;
        hsX[(sk + 3) * 4 + (ln & 3)] = hv.w;
        asm volatile("s_waitcnt lgkmcnt(0)" ::: "memory");   // wave-local visibility

        // ---- FMA: 2 units x 4 gates x 4 batches x 16 k, packed fp32 pairs ----
        f2_t ae0l={0,0}, ae0h={0,0}, ae1l={0,0}, ae1h={0,0};
        f2_t ae2l={0,0}, ae2h={0,0}, ae3l={0,0}, ae3h={0,0};
        f2_t ao0l={0,0}, ao0h={0,0}, ao1l={0,0}, ao1h={0,0};
        f2_t ao2l={0,0}, ao2h={0,0}, ao3l={0,0}, ao3h={0,0};
#pragma unroll
        for (int j = 0; j < 16; ++j) {
            float4 h4 = hsX4[ks * 16 + j];        // h[k][4b of this half]
            f2_t hx = {h4.x, h4.x}, hy = {h4.y, h4.y};
            f2_t hz = {h4.z, h4.z}, hw = {h4.w, h4.w};
            f2_t wel = We[j].lo, weh = We[j].hi;
            f2_t wol = Wo[j].lo, woh = Wo[j].hi;
            ae0l = __builtin_elementwise_fma(wel, hx, ae0l);
            ae0h = __builtin_elementwise_fma(weh, hx, ae0h);
            ae1l = __builtin_elementwise_fma(wel, hy, ae1l);
            ae1h = __builtin_elementwise_fma(weh, hy, ae1h);
            ae2l = __builtin_elementwise_fma(wel, hz, ae2l);
            ae2h = __builtin_elementwise_fma(weh, hz, ae2h);
            ae3l = __builtin_elementwise_fma(wel, hw, ae3l);
            ae3h = __builtin_elementwise_fma(weh, hw, ae3h);
            ao0l = __builtin_elementwise_fma(wol, hx, ao0l);
            ao0h = __builtin_elementwise_fma(woh, hx, ao0h);
            ao1l = __builtin_elementwise_fma(wol, hy, ao1l);
            ao1h = __builtin_elementwise_fma(woh, hy, ao1h);
            ao2l = __builtin_elementwise_fma(wol, hz, ao2l);
            ao2h = __builtin_elementwise_fma(woh, hz, ao2h);
            ao3l = __builtin_elementwise_fma(wol, hw, ao3l);
            ao3h = __builtin_elementwise_fma(woh, hw, ao3h);
        }
        // ---- write partials (layout identical to r12) ----
        {
            float4* r = &red4[((wv * 4 + kssub) * 16 + upair) * 11 + kssub];
            r[0] = make_float4(ae0l.x, ae0l.y, ae0h.x, ae0h.y);
            r[1] = make_float4(ae1l.x, ae1l.y, ae1h.x, ae1h.y);
            r[2] = make_float4(ae2l.x, ae2l.y, ae2h.x, ae2h.y);
            r[3] = make_float4(ae3l.x, ae3l.y, ae3h.x, ae3h.y);
            r[4] = make_float4(ao0l.x, ao0l.y, ao0h.x, ao0h.y);
            r[5] = make_float4(ao1l.x, ao1l.y, ao1h.x, ao1h.y);
            r[6] = make_float4(ao2l.x, ao2l.y, ao2h.x, ao2h.y);
            r[7] = make_float4(ao3l.x, ao3l.y, ao3h.x, ao3h.y);
        }
        asm volatile("s_waitcnt lgkmcnt(0)\n\ts_barrier" ::: "memory");   // barrier 1

        // ---- act reduction: ALL 64 lanes; shfl_xor(32) combines halves ----
        bool gissue = false;
        {
            const int b = wv, u = ln & 31, half = ln >> 5;
            const int bhv = b >> 2, bq = b & 3, up = u >> 1, par = u & 1;
            float rx = 0.f, ry = 0.f, rz = 0.f, rw = 0.f;
#pragma unroll
            for (int kq2 = 0; kq2 < 2; ++kq2) {
                const int kq = half * 2 + kq2;
#pragma unroll
                for (int kr = 0; kr < 4; ++kr) {
                    float4 p = red4[(((kq * 2 + bhv) * 4 + kr) * 16 + up) * 11 + kr + par * 4 + bq];
                    rx += p.x; ry += p.y; rz += p.z; rw += p.w;
                }
            }
            float ox = __shfl_xor(rx, 32);
            float oy = __shfl_xor(ry, 32);
            float oz = __shfl_xor(rz, 32);
            float ow = __shfl_xor(rw, 32);
            if (is_act) {
                // gpend (G for step t) was issued newest last step; ~1300cy have
                // elapsed (stage wait + transpose + FMA + barrier) -> near-free.
                asm volatile("s_waitcnt vmcnt(0)" : "+v"(gpend) :: "memory");
                if (!gok) {                       // gp not validated: poll + LLC reload
                    const int byc = t >> 2;
                    int itc = 0;
                    while (__hip_atomic_load(gcnt + dir * 64 + byc, __ATOMIC_RELAXED,
                                             __HIP_MEMORY_SCOPE_AGENT) < 8) {
                        __builtin_amdgcn_s_sleep(2);
                        if (++itc > (1 << 22)) break;
                    }
                    const float* gsrc = Gd + ((size_t)t * B_ + bt * 8 + b) * NG_ + (size_t)(ut * 32 + u) * 4;
                    asm volatile("global_load_dwordx4 %0, %1, off sc0 sc1\n\ts_waitcnt vmcnt(0)"
                                 : "=v"(gpend) : "v"(gsrc) : "memory");
                }
                float si = gpend.x + rx + ox;
                float sf = gpend.y + ry + oy;
                float sg = gpend.z + rz + oz;
                float so = gpend.w + rw + ow;
                c = sigfast(sf) * c + sigfast(si) * tanhfast(sg);
                float h = sigfast(so) * tanhfast(c);
                // publish FIRST (gets the store into flight), then local copy
                float* dst = hexg + (size_t)t * 2048 + b * 256 + ut * 32 + u;
                asm volatile("global_store_dword %0, %1, off sc0 sc1" :: "v"(dst), "v"(h) : "memory");
                ((float*)hT4)[b * 32 + u] = h;
                if (t + 1 < Tmax) {               // readiness check for G(t+1)
                    const int byn = (t + 1) >> 2;
                    if (byn > gready) {
                        int la = byn + 7; if (la > 63) la = 63;
                        if (__hip_atomic_load(gcnt + dir * 64 + la, __ATOMIC_RELAXED,
                                              __HIP_MEMORY_SCOPE_AGENT) >= 8) gready = la;
                        else if (__hip_atomic_load(gcnt + dir * 64 + byn, __ATOMIC_RELAXED,
                                                   __HIP_MEMORY_SCOPE_AGENT) >= 8) gready = byn;
                    }
                    if (byn <= gready) { gissue = true; gok = 1; }
                    else gok = 0;                 // skip -> no stale pull; reload next step
                }
            }
        }
        // ---- pre-issue next step's poll (after publish; overlaps barrier) ----
        if (t + 1 < Tmax && speer != ut) {
            const float* nsrc = hexg + (size_t)t * 2048 + sb * 256 + sk;
            asm volatile("global_load_dwordx4 %0, %1, off sc0 sc1"
                         : "=v"(pend) : "v"(nsrc) : "memory");
        }
        // ---- G prefetch issue (NEWEST VMEM op of the step; skipped by stage wait) ----
        if (gissue) {
            const float* gsrc = Gd + ((size_t)(t + 1) * B_ + bt * 8 + wv) * NG_
                                + (size_t)(ut * 32 + (ln & 31)) * 4;
            asm volatile("global_load_dwordx4 %0, %1, off"
                         : "=v"(gpend) : "v"(gsrc) : "memory");
        }
        gi = (__ballot(gissue) != 0ull) ? 1 : 0;   // wave-uniform
        asm volatile("s_waitcnt lgkmcnt(0)\n\ts_barrier" ::: "memory");   // barrier 2
    }
}

// ---------- Viterbi + backtrace: single block, feats prefetch, bp nibble-packed ----------
__global__ __launch_bounds__(512) void viterbi_k(
    const float* __restrict__ feats, const float* __restrict__ trans,
    const int* __restrict__ lens, float* __restrict__ out) {
    __shared__ float fv[2][B_][16];
    __shared__ float tl[K_][16];
    __shared__ unsigned char bp[T_][B_][6];    // 4-bit backpointers, 48KB
    __shared__ int best_last[B_];
    int tid = threadIdx.x;
    int b = tid >> 4, lane = tid & 15;
    if (tid < K_ * K_) tl[tid / 12][tid % 12] = trans[tid];
    if (lane < K_) fv[0][b][lane] = (lane == START_) ? 0.f : NEG_;
    __syncthreads();
    int len = lens[b];
    int pp = 0;
    float f_cur = 0.f;
    if (lane < K_) f_cur = feats[(size_t)b * T_ * K_ + lane];
    for (int t = 0; t < T_; ++t) {
        float f_nxt = 0.f;                       // prefetch t+1 before the compute chain
        if (t + 1 < T_ && lane < K_) f_nxt = feats[((size_t)b * T_ + t + 1) * K_ + lane];
        if (lane < K_) {
            float best = fv[pp][b][0] + tl[lane][0];
            int argp = 0;
#pragma unroll
            for (int p = 1; p < K_; ++p) {
                float v = fv[pp][b][p] + tl[lane][p];
                if (v > best) { best = v; argp = p; }   // strict > = first-max (matches jnp.argmax)
            }
            float nb = best + f_cur;
            fv[pp ^ 1][b][lane] = (t < len) ? nb : fv[pp][b][lane];
            int other = __shfl_xor(argp, 1);
            if ((lane & 1) == 0) bp[t][b][lane >> 1] = (unsigned char)(argp | (other << 4));
        }
        __syncthreads();
        pp ^= 1;
        f_cur = f_nxt;
    }
    if (lane == 0) {
        float best = fv[pp][b][0] + tl[STOP_][0];
        int bl = 0;
#pragma unroll
        for (int p = 1; p < K_; ++p) {
            float v = fv[pp][b][p] + tl[STOP_][p];
            if (v > best) { best = v; bl = p; }
        }
        out[b] = best;
        best_last[b] = bl;
    }
    __syncthreads();
    if (lane == 0) {
        int tag = best_last[b];
        for (int t = T_ - 1; t >= 0; --t) {
            int m = (t < len);
            out[B_ + b * T_ + t] = (float)(m ? tag : -1);
            if (m) tag = (bp[t][b][tag >> 1] >> ((tag & 1) * 4)) & 15;
        }
    }
}

extern "C" void kernel_launch(void* const* d_in, const int* in_sizes, int n_in,
                              void* d_out, int out_size, void* d_ws, size_t ws_size,
                              hipStream_t stream) {
    const int*   sent  = (const int*)d_in[0];
    const int*   lens  = (const int*)d_in[1];
    const float* emb   = (const float*)d_in[2];
    const float* Wih_f = (const float*)d_in[3];
    const float* Whh_f = (const float*)d_in[4];
    const float* bih_f = (const float*)d_in[5];
    const float* bhh_f = (const float*)d_in[6];
    const float* Wih_b = (const float*)d_in[7];
    const float* Whh_b = (const float*)d_in[8];
    const float* bih_b = (const float*)d_in[9];
    const float* bhh_b = (const float*)d_in[10];
    const float* h0    = (const float*)d_in[11];
    const float* c0    = (const float*)d_in[12];
    const float* Wout  = (const float*)d_in[13];
    const float* bout  = (const float*)d_in[14];
    const float* trans = (const float*)d_in[15];
    float* out = (float*)d_out;

    char* ws = (char*)d_ws;
    int*   tokA  = (int*)ws;                                  // 64 KB
    float* WhhT  = (float*)(ws + 65536);                      // 2 MB
    float* G     = (float*)(ws + 2162688);                    // 67.1 MB
    float* feats = (float*)(ws + 69271552);                   // 0.39 MB
    float* hex   = (float*)(ws + 69664768);                   // 16 MB  [8 groups][T][2048]
    // gcnt: 128 ints in d_out's preds region (out[32..159]); zeroed by prep,
    // fully overwritten by viterbi_k at the end. feats region is written
    // concurrently by the feat role, so an overlay there would race.
    int*   gcnt  = (int*)(out + 32);

    prep<<<4672, 256, 0, stream>>>(sent, lens, tokA, Whh_f, Whh_b, WhhT, hex, gcnt);
    mega<<<1344, 512, 0, stream>>>(emb, tokA, Wih_f, Wih_b, bih_f, bhh_f, bih_b, bhh_b,
                                   WhhT, G, h0, c0, lens, hex, gcnt, Wout, bout, feats);
    viterbi_k<<<1, 512, 0, stream>>>(feats, trans, lens, out);
}